// Round 5
// baseline (492.097 us; speedup 1.0000x reference)
//
#include <hip/hip_runtime.h>

#define NODES   50000
#define EDGES   800000
#define GRAPHS  500
#define HID     128
#define OUTC    10
#define NLAYERS 3
#define NBUCK   ((NODES + 63) / 64)   // 782

typedef __bf16 bf16x8 __attribute__((ext_vector_type(8)));
typedef float  f32x4  __attribute__((ext_vector_type(4)));

__device__ __forceinline__ unsigned short f2bf(float f){
    unsigned u = __float_as_uint(f);
    u = (u + 0x7fffu + ((u >> 16) & 1u)) >> 16;
    return (unsigned short)u;
}
__device__ __forceinline__ float bf2f(unsigned short h){
    return __uint_as_float(((unsigned)h) << 16);
}

// ---------------------------------------------------------------------------
// CSR build
// ---------------------------------------------------------------------------
__global__ __launch_bounds__(256) void degree_kernel(
    const int* __restrict__ dst, int* __restrict__ deg)
{
    int e = blockIdx.x * 256 + threadIdx.x;
    if (e < EDGES) atomicAdd(&deg[dst[e]], 1);
}

__global__ __launch_bounds__(256) void scan_partial_kernel(
    const int* __restrict__ deg, int* __restrict__ bsum)
{
    __shared__ int s[256];
    int i = blockIdx.x * 256 + threadIdx.x;
    int v = (i < NODES) ? deg[i] : 0;
    s[threadIdx.x] = v;
    __syncthreads();
    for (int off = 128; off > 0; off >>= 1) {
        if (threadIdx.x < off) s[threadIdx.x] += s[threadIdx.x + off];
        __syncthreads();
    }
    if (threadIdx.x == 0) bsum[blockIdx.x] = s[0];
}

__global__ __launch_bounds__(256) void scan_small_kernel(
    const int* __restrict__ bsum, int* __restrict__ boff)
{
    __shared__ int s[256];
    const int t = threadIdx.x;
    const int nb = (NODES + 255) / 256;     // 196
    int v = (t < nb) ? bsum[t] : 0;
    s[t] = v;
    __syncthreads();
    for (int off = 1; off < 256; off <<= 1) {
        int u = (t >= off) ? s[t - off] : 0;
        __syncthreads();
        s[t] += u;
        __syncthreads();
    }
    if (t < nb) boff[t] = s[t] - v;         // exclusive
}

// block-local scan + block offset -> rowptr, cursor, and bucket cursors
__global__ __launch_bounds__(256) void scan_final_kernel(
    int* __restrict__ cursor,
    const int* __restrict__ boff,
    int* __restrict__ rowptr,
    int* __restrict__ bcursor)
{
    __shared__ int s[256];
    const int t = threadIdx.x;
    const int i = blockIdx.x * 256 + t;
    int v = (i < NODES) ? cursor[i] : 0;
    s[t] = v;
    __syncthreads();
    for (int off = 1; off < 256; off <<= 1) {
        int u = (t >= off) ? s[t - off] : 0;
        __syncthreads();
        s[t] += u;
        __syncthreads();
    }
    if (i < NODES) {
        int excl = s[t] - v + boff[blockIdx.x];
        rowptr[i] = excl;
        cursor[i] = excl;
        if ((i & 63) == 0) bcursor[i >> 6] = excl;   // bucket = node/64
    }
    if (blockIdx.x == 0 && t == 0) rowptr[NODES] = EDGES;
}

// Phase 1: scatter packed (dst,src) into per-bucket regions (8B, stream-local)
__global__ __launch_bounds__(256) void bucket_kernel(
    const int* __restrict__ src, const int* __restrict__ dst,
    int* __restrict__ bcursor, unsigned long long* __restrict__ ep)
{
    int e = blockIdx.x * 256 + threadIdx.x;
    if (e < EDGES) {
        int d = dst[e], s = src[e];
        int pos = atomicAdd(&bcursor[d >> 6], 1);
        ep[pos] = ((unsigned long long)(unsigned)d << 32) | (unsigned)s;
    }
}

// Phase 2: coalesced read of bucket-sorted edges; scatter src within 4KB window
__global__ __launch_bounds__(256) void fill2_kernel(
    const unsigned long long* __restrict__ ep,
    int* __restrict__ cursor, int* __restrict__ csr)
{
    int e = blockIdx.x * 256 + threadIdx.x;
    if (e < EDGES) {
        unsigned long long v = ep[e];
        int d = (int)(v >> 32), s = (int)(v & 0xffffffffu);
        int pos = atomicAdd(&cursor[d], 1);
        csr[pos] = s;
    }
}

// ---------------------------------------------------------------------------
// Weight prep: wt[m][n][k] = bf16(w[m][k][n]), m = 0..2 -> w1, 3..5 -> w2
// ---------------------------------------------------------------------------
__global__ __launch_bounds__(256) void prep_w_kernel(
    const float* __restrict__ w1, const float* __restrict__ w2,
    unsigned short* __restrict__ wt)
{
    int idx = blockIdx.x * 256 + threadIdx.x;
    if (idx >= 6 * HID * HID) return;
    int m = idx >> 14;
    int n = (idx >> 7) & 127;
    int k = idx & 127;
    const float* w = (m < 3) ? (w1 + (size_t)m * HID * HID)
                             : (w2 + (size_t)(m - 3) * HID * HID);
    wt[idx] = f2bf(w[(size_t)k * HID + n]);
}

// ---------------------------------------------------------------------------
// x f32 -> bf16 (packed pairs)
// ---------------------------------------------------------------------------
__global__ __launch_bounds__(256) void conv_kernel(
    const float* __restrict__ x, unsigned* __restrict__ xb)
{
    int i = blockIdx.x * 256 + threadIdx.x;   // pair index
    if (i >= NODES * 64) return;
    float2 v = reinterpret_cast<const float2*>(x)[i];
    xb[i] = ((unsigned)f2bf(v.y) << 16) | f2bf(v.x);
}

// ---------------------------------------------------------------------------
// Gather, 16 edges in flight: one wave per node, quarter-wave per neighbor
// row (16 lanes x dwordx4 = 256 B = full bf16 row), 4 unrolled per quarter.
// Branchless: clamp edge index, mask contribution.
// ---------------------------------------------------------------------------
__global__ __launch_bounds__(256) void gather4_kernel(
    const unsigned short* __restrict__ x,
    const int* __restrict__ rowptr, const int* __restrict__ csr,
    unsigned short* __restrict__ hin)
{
    const int w    = threadIdx.x >> 6;
    const int lane = threadIdx.x & 63;
    const int n    = blockIdx.x * 4 + w;
    if (n >= NODES) return;
    const int q  = lane >> 4;      // quarter 0..3 -> neighbor slot
    const int lr = lane & 15;      // 16B chunk within row

    const uint4* xr = reinterpret_cast<const uint4*>(x);   // 16 uint4 per row

    float acc[8];
    #pragma unroll
    for (int i = 0; i < 8; ++i) acc[i] = 0.f;

    const int lo = rowptr[n], hi = rowptr[n + 1];
    for (int e0 = lo; e0 < hi; e0 += 16) {
        uint4 v[4];
        unsigned m[4];
        #pragma unroll
        for (int j = 0; j < 4; ++j) {
            int e = e0 + 4 * j + q;
            bool ok = e < hi;
            m[j] = ok ? 0xffffffffu : 0u;
            int ec = ok ? e : (hi - 1);          // always-valid load address
            v[j] = xr[(size_t)csr[ec] * 16 + lr];
        }
        #pragma unroll
        for (int j = 0; j < 4; ++j) {
            const unsigned uu[4] = {v[j].x, v[j].y, v[j].z, v[j].w};
            #pragma unroll
            for (int k2 = 0; k2 < 4; ++k2) {
                unsigned uv = uu[k2] & m[j];
                acc[2 * k2]     += __uint_as_float(uv << 16);
                acc[2 * k2 + 1] += __uint_as_float(uv & 0xffff0000u);
            }
        }
    }

    #pragma unroll
    for (int i = 0; i < 8; ++i) {
        acc[i] += __shfl_xor(acc[i], 16, 64);
        acc[i] += __shfl_xor(acc[i], 32, 64);
    }

    if (q == 0) {
        uint4 self = xr[(size_t)n * 16 + lr];
        const unsigned su[4] = {self.x, self.y, self.z, self.w};
        uint4 o;
        unsigned* ou = &o.x;
        #pragma unroll
        for (int j = 0; j < 4; ++j) {
            float c0 = acc[2 * j]     + __uint_as_float(su[j] << 16);
            float c1 = acc[2 * j + 1] + __uint_as_float(su[j] & 0xffff0000u);
            ou[j] = ((unsigned)f2bf(c1) << 16) | f2bf(c0);
        }
        reinterpret_cast<uint4*>(hin)[(size_t)n * 16 + lr] = o;
    }
}

// ---------------------------------------------------------------------------
// Fused dual MFMA GEMM: C = relu( relu(A@W1+b1) @ W2 + b2 ), bf16 in/out.
// 128-row tile, 4 waves; each wave owns a 32-row stripe (2 row-sets of 16)
// sharing every W fragment across both row-sets (2x MFMA per W load, 16
// independent accumulation chains). h1 kept in wave-private LDS rows.
// ---------------------------------------------------------------------------
__global__ __launch_bounds__(256) void gemm_dual_kernel(
    const unsigned short* __restrict__ A,
    const unsigned short* __restrict__ Wt1, const float* __restrict__ bias1,
    const unsigned short* __restrict__ Wt2, const float* __restrict__ bias2,
    unsigned short* __restrict__ C,
    int M)
{
    __shared__ unsigned short As[128][136];
    const int tid  = threadIdx.x;
    const int row0 = blockIdx.x * 128;

    #pragma unroll
    for (int j = 0; j < 8; ++j) {
        int chunk = tid + 256 * j;          // 0..2047
        int r  = chunk >> 4;                // 0..127
        int cw = chunk & 15;
        int gr = row0 + r;
        uint4 v = make_uint4(0u, 0u, 0u, 0u);
        if (gr < M) v = *reinterpret_cast<const uint4*>(A + (size_t)gr * HID + cw * 8);
        *reinterpret_cast<uint4*>(&As[r][cw * 8]) = v;
    }
    __syncthreads();

    const int w    = tid >> 6;
    const int lane = tid & 63;
    const int lr   = lane & 15;
    const int lg   = lane >> 4;
    const int ar0  = w * 32 + lr;       // row-set 0
    const int ar1  = ar0 + 16;          // row-set 1

    bf16x8 af0[4], af1[4];
    f32x4 acc0[8], acc1[8];

    // ---- GEMM 1 ----
    #pragma unroll
    for (int s = 0; s < 4; ++s) {
        af0[s] = *reinterpret_cast<const bf16x8*>(&As[ar0][s * 32 + lg * 8]);
        af1[s] = *reinterpret_cast<const bf16x8*>(&As[ar1][s * 32 + lg * 8]);
    }
    #pragma unroll
    for (int nt = 0; nt < 8; ++nt) {
        acc0[nt] = (f32x4){0.f, 0.f, 0.f, 0.f};
        acc1[nt] = (f32x4){0.f, 0.f, 0.f, 0.f};
    }
    {
        const unsigned short* wp = Wt1 + (size_t)lr * HID + lg * 8;
        #pragma unroll
        for (int nt = 0; nt < 8; ++nt) {
            const unsigned short* wn = wp + (size_t)nt * 16 * HID;
            #pragma unroll
            for (int s = 0; s < 4; ++s) {
                bf16x8 b = *reinterpret_cast<const bf16x8*>(wn + s * 32);
                acc0[nt] = __builtin_amdgcn_mfma_f32_16x16x32_bf16(b, af0[s], acc0[nt], 0, 0, 0);
                acc1[nt] = __builtin_amdgcn_mfma_f32_16x16x32_bf16(b, af1[s], acc1[nt], 0, 0, 0);
            }
        }
    }

    // bias1 + relu -> h1 back into LDS (wave-private rows)
    {
        const float4* b4p = reinterpret_cast<const float4*>(bias1);
        #pragma unroll
        for (int nt = 0; nt < 8; ++nt) {
            float4 b4 = b4p[nt * 4 + lg];
            ushort4 o0, o1;
            o0.x = f2bf(fmaxf(acc0[nt][0] + b4.x, 0.f));
            o0.y = f2bf(fmaxf(acc0[nt][1] + b4.y, 0.f));
            o0.z = f2bf(fmaxf(acc0[nt][2] + b4.z, 0.f));
            o0.w = f2bf(fmaxf(acc0[nt][3] + b4.w, 0.f));
            o1.x = f2bf(fmaxf(acc1[nt][0] + b4.x, 0.f));
            o1.y = f2bf(fmaxf(acc1[nt][1] + b4.y, 0.f));
            o1.z = f2bf(fmaxf(acc1[nt][2] + b4.z, 0.f));
            o1.w = f2bf(fmaxf(acc1[nt][3] + b4.w, 0.f));
            *reinterpret_cast<ushort4*>(&As[ar0][nt * 16 + lg * 4]) = o0;
            *reinterpret_cast<ushort4*>(&As[ar1][nt * 16 + lg * 4]) = o1;
        }
    }

    // ---- GEMM 2 ----
    #pragma unroll
    for (int s = 0; s < 4; ++s) {
        af0[s] = *reinterpret_cast<const bf16x8*>(&As[ar0][s * 32 + lg * 8]);
        af1[s] = *reinterpret_cast<const bf16x8*>(&As[ar1][s * 32 + lg * 8]);
    }
    #pragma unroll
    for (int nt = 0; nt < 8; ++nt) {
        acc0[nt] = (f32x4){0.f, 0.f, 0.f, 0.f};
        acc1[nt] = (f32x4){0.f, 0.f, 0.f, 0.f};
    }
    {
        const unsigned short* wp = Wt2 + (size_t)lr * HID + lg * 8;
        #pragma unroll
        for (int nt = 0; nt < 8; ++nt) {
            const unsigned short* wn = wp + (size_t)nt * 16 * HID;
            #pragma unroll
            for (int s = 0; s < 4; ++s) {
                bf16x8 b = *reinterpret_cast<const bf16x8*>(wn + s * 32);
                acc0[nt] = __builtin_amdgcn_mfma_f32_16x16x32_bf16(b, af0[s], acc0[nt], 0, 0, 0);
                acc1[nt] = __builtin_amdgcn_mfma_f32_16x16x32_bf16(b, af1[s], acc1[nt], 0, 0, 0);
            }
        }
    }

    const int r0 = row0 + ar0;
    const int r1 = row0 + ar1;
    {
        const float4* b4p = reinterpret_cast<const float4*>(bias2);
        #pragma unroll
        for (int nt = 0; nt < 8; ++nt) {
            int col = nt * 16 + lg * 4;
            float4 b4 = b4p[nt * 4 + lg];
            if (r0 < M) {
                ushort4 o;
                o.x = f2bf(fmaxf(acc0[nt][0] + b4.x, 0.f));
                o.y = f2bf(fmaxf(acc0[nt][1] + b4.y, 0.f));
                o.z = f2bf(fmaxf(acc0[nt][2] + b4.z, 0.f));
                o.w = f2bf(fmaxf(acc0[nt][3] + b4.w, 0.f));
                *reinterpret_cast<ushort4*>(C + (size_t)r0 * HID + col) = o;
            }
            if (r1 < M) {
                ushort4 o;
                o.x = f2bf(fmaxf(acc1[nt][0] + b4.x, 0.f));
                o.y = f2bf(fmaxf(acc1[nt][1] + b4.y, 0.f));
                o.z = f2bf(fmaxf(acc1[nt][2] + b4.z, 0.f));
                o.w = f2bf(fmaxf(acc1[nt][3] + b4.w, 0.f));
                *reinterpret_cast<ushort4*>(C + (size_t)r1 * HID + col) = o;
            }
        }
    }
}

// ---------------------------------------------------------------------------
// Pool over sorted batch ids (bf16 in, f32 out)
// ---------------------------------------------------------------------------
__device__ __forceinline__ int lbound(const int* __restrict__ a, int v)
{
    int lo = 0, hi = NODES;
    while (lo < hi) {
        int m = (lo + hi) >> 1;
        if (a[m] < v) lo = m + 1; else hi = m;
    }
    return lo;
}

__global__ __launch_bounds__(256) void pool_sorted_kernel(
    const unsigned short* __restrict__ x,
    const int* __restrict__ batch,
    float* __restrict__ g)
{
    const int gid = blockIdx.x;
    const int beg = lbound(batch, gid);
    const int end = lbound(batch, gid + 1);

    const int c    = threadIdx.x & 127;
    const int half = threadIdx.x >> 7;

    float acc = 0.f;
    for (int r = beg + half; r < end; r += 2)
        acc += bf2f(x[(size_t)r * HID + c]);

    __shared__ float lds[256];
    lds[threadIdx.x] = acc;
    __syncthreads();
    if (threadIdx.x < 128)
        g[(size_t)gid * HID + threadIdx.x] = lds[threadIdx.x] + lds[threadIdx.x + 128];
}

// ---------------------------------------------------------------------------
// Small f32 GEMM for the graph-level MLP (M=500)
// ---------------------------------------------------------------------------
__global__ __launch_bounds__(256) void gemm128_f32_kernel(
    const float* __restrict__ A,
    const float* __restrict__ W,
    const float* __restrict__ bias,
    float* __restrict__ C,
    int M)
{
    __shared__ float As[32][HID];
    const int tid  = threadIdx.x;
    const int row0 = blockIdx.x * 32;

    {
        const int r = tid >> 3;
        const int c = (tid & 7) * 16;
        const int gr = row0 + r;
        float4* ps = reinterpret_cast<float4*>(&As[r][c]);
        if (gr < M) {
            const float4* pa = reinterpret_cast<const float4*>(A + (size_t)gr * HID + c);
            #pragma unroll
            for (int j = 0; j < 4; ++j) ps[j] = pa[j];
        } else {
            #pragma unroll
            for (int j = 0; j < 4; ++j) ps[j] = make_float4(0.f, 0.f, 0.f, 0.f);
        }
    }
    __syncthreads();

    const int tx = tid & 31;
    const int ty = tid >> 5;

    float4 acc[4];
    #pragma unroll
    for (int i = 0; i < 4; ++i) acc[i] = make_float4(0.f, 0.f, 0.f, 0.f);

    #pragma unroll 4
    for (int k = 0; k < HID; ++k) {
        const float4 w = *reinterpret_cast<const float4*>(W + (size_t)k * HID + tx * 4);
        #pragma unroll
        for (int i = 0; i < 4; ++i) {
            const float a = As[ty + 8 * i][k];
            acc[i].x += a * w.x;
            acc[i].y += a * w.y;
            acc[i].z += a * w.z;
            acc[i].w += a * w.w;
        }
    }

    const float4 b4 = *reinterpret_cast<const float4*>(bias + tx * 4);
    #pragma unroll
    for (int i = 0; i < 4; ++i) {
        const int row = row0 + ty + 8 * i;
        if (row < M) {
            float4 o = make_float4(fmaxf(acc[i].x + b4.x, 0.f),
                                   fmaxf(acc[i].y + b4.y, 0.f),
                                   fmaxf(acc[i].z + b4.z, 0.f),
                                   fmaxf(acc[i].w + b4.w, 0.f));
            *reinterpret_cast<float4*>(C + (size_t)row * HID + tx * 4) = o;
        }
    }
}

__global__ __launch_bounds__(256) void final_kernel(
    const float* __restrict__ gh,
    const float* __restrict__ w2,
    const float* __restrict__ b2,
    float* __restrict__ out)
{
    int idx = blockIdx.x * 256 + threadIdx.x;
    int r = idx >> 4;
    int c = idx & 15;
    if (r >= GRAPHS || c >= OUTC) return;
    float acc = b2[c];
    for (int k = 0; k < HID; ++k)
        acc += gh[(size_t)r * HID + k] * w2[(size_t)k * OUTC + c];
    out[(size_t)r * OUTC + c] = acc;
}

// ---------------------------------------------------------------------------
extern "C" void kernel_launch(void* const* d_in, const int* in_sizes, int n_in,
                              void* d_out, int out_size, void* d_ws, size_t ws_size,
                              hipStream_t stream)
{
    const float* x    = (const float*)d_in[0];
    const float* w1   = (const float*)d_in[1];
    const float* b1   = (const float*)d_in[2];
    const float* w2   = (const float*)d_in[3];
    const float* b2   = (const float*)d_in[4];
    const float* mw1  = (const float*)d_in[5];
    const float* mb1  = (const float*)d_in[6];
    const float* mw2  = (const float*)d_in[7];
    const float* mb2  = (const float*)d_in[8];
    const int*   ei   = (const int*)d_in[9];
    const int*   batch= (const int*)d_in[10];
    float* out = (float*)d_out;

    // workspace layout
    char* p = (char*)d_ws;
    unsigned long long* ep = (unsigned long long*)p;  p += (size_t)EDGES * 8;   // 8B-aligned first
    unsigned short* bufB = (unsigned short*)p;  p += (size_t)NODES * HID * 2;
    unsigned short* t0   = (unsigned short*)p;  p += (size_t)NODES * HID * 2;
    unsigned short* wt   = (unsigned short*)p;  p += (size_t)6 * HID * HID * 2;
    float* g      = (float*)p;                  p += (size_t)GRAPHS * HID * 4;
    float* gh     = (float*)p;                  p += (size_t)GRAPHS * HID * 4;
    int*   cursor = (int*)p;                    p += (size_t)NODES * 4;
    int*   rowptr = (int*)p;                    p += (size_t)(NODES + 1) * 4;
    int*   csr    = (int*)p;                    p += (size_t)EDGES * 4;
    int*   bsum   = (int*)p;                    p += 256 * 4;
    int*   boff   = (int*)p;                    p += 256 * 4;
    int*   bcursor= (int*)p;

    const int* src = ei;
    const int* dst = ei + EDGES;

    const dim3 blk(256);
    const int edgeBlocks   = (EDGES + 255) / 256;       // 3125
    const int scanBlocks   = (NODES + 255) / 256;       // 196
    const int gatherBlocks = (NODES + 3) / 4;           // 12500
    const int gemmBlocks   = (NODES + 127) / 128;       // 391
    const int convBlocks   = (NODES * 64 + 255) / 256;  // 12500

    // ---- CSR build + weight/x prep ----
    hipMemsetAsync(cursor, 0, (size_t)NODES * sizeof(int), stream);
    degree_kernel<<<edgeBlocks, blk, 0, stream>>>(dst, cursor);
    scan_partial_kernel<<<scanBlocks, blk, 0, stream>>>(cursor, bsum);
    scan_small_kernel<<<1, blk, 0, stream>>>(bsum, boff);
    scan_final_kernel<<<scanBlocks, blk, 0, stream>>>(cursor, boff, rowptr, bcursor);
    bucket_kernel<<<edgeBlocks, blk, 0, stream>>>(src, dst, bcursor, ep);
    fill2_kernel<<<edgeBlocks, blk, 0, stream>>>(ep, cursor, csr);
    prep_w_kernel<<<(6 * HID * HID + 255) / 256, blk, 0, stream>>>(w1, w2, wt);
    conv_kernel<<<convBlocks, blk, 0, stream>>>(x, (unsigned*)bufB);

    // ---- 3 GIN layers: gather(bufB->t0); dual-gemm(t0->bufB) ----
    for (int l = 0; l < NLAYERS; ++l) {
        gather4_kernel<<<gatherBlocks, blk, 0, stream>>>(bufB, rowptr, csr, t0);
        gemm_dual_kernel<<<gemmBlocks, blk, 0, stream>>>(
            t0,
            wt + (size_t)l * HID * HID,       b1 + (size_t)l * HID,
            wt + (size_t)(l + 3) * HID * HID, b2 + (size_t)l * HID,
            bufB, NODES);
    }

    // ---- pool + MLP ----
    pool_sorted_kernel<<<GRAPHS, blk, 0, stream>>>(bufB, batch, g);
    gemm128_f32_kernel<<<(GRAPHS + 31) / 32, blk, 0, stream>>>(g, mw1, mb1, gh, GRAPHS);
    final_kernel<<<(GRAPHS * 16 + 255) / 256, blk, 0, stream>>>(gh, mw2, mb2, out);
}

// Round 6
// 326.419 us; speedup vs baseline: 1.5076x; 1.5076x over previous
//
#include <hip/hip_runtime.h>

#define NODES   50000
#define EDGES   800000
#define GRAPHS  500
#define HID     128
#define OUTC    10
#define NLAYERS 3

typedef __bf16 bf16x8 __attribute__((ext_vector_type(8)));
typedef float  f32x4  __attribute__((ext_vector_type(4)));

__device__ __forceinline__ unsigned short f2bf(float f){
    unsigned u = __float_as_uint(f);
    u = (u + 0x7fffu + ((u >> 16) & 1u)) >> 16;
    return (unsigned short)u;
}
__device__ __forceinline__ float bf2f(unsigned short h){
    return __uint_as_float(((unsigned)h) << 16);
}

// ---------------------------------------------------------------------------
// CSR build
// ---------------------------------------------------------------------------
__global__ __launch_bounds__(256) void degree_kernel(
    const int* __restrict__ dst, int* __restrict__ deg)
{
    int e = blockIdx.x * 256 + threadIdx.x;
    if (e < EDGES) atomicAdd(&deg[dst[e]], 1);
}

__global__ __launch_bounds__(256) void scan_partial_kernel(
    const int* __restrict__ deg, int* __restrict__ bsum)
{
    __shared__ int s[256];
    int i = blockIdx.x * 256 + threadIdx.x;
    int v = (i < NODES) ? deg[i] : 0;
    s[threadIdx.x] = v;
    __syncthreads();
    for (int off = 128; off > 0; off >>= 1) {
        if (threadIdx.x < off) s[threadIdx.x] += s[threadIdx.x + off];
        __syncthreads();
    }
    if (threadIdx.x == 0) bsum[blockIdx.x] = s[0];
}

__global__ __launch_bounds__(256) void scan_small_kernel(
    const int* __restrict__ bsum, int* __restrict__ boff)
{
    __shared__ int s[256];
    const int t = threadIdx.x;
    const int nb = (NODES + 255) / 256;     // 196
    int v = (t < nb) ? bsum[t] : 0;
    s[t] = v;
    __syncthreads();
    for (int off = 1; off < 256; off <<= 1) {
        int u = (t >= off) ? s[t - off] : 0;
        __syncthreads();
        s[t] += u;
        __syncthreads();
    }
    if (t < nb) boff[t] = s[t] - v;         // exclusive
}

__global__ __launch_bounds__(256) void scan_final_kernel(
    int* __restrict__ cursor,
    const int* __restrict__ boff,
    int* __restrict__ rowptr)
{
    __shared__ int s[256];
    const int t = threadIdx.x;
    const int i = blockIdx.x * 256 + t;
    int v = (i < NODES) ? cursor[i] : 0;
    s[t] = v;
    __syncthreads();
    for (int off = 1; off < 256; off <<= 1) {
        int u = (t >= off) ? s[t - off] : 0;
        __syncthreads();
        s[t] += u;
        __syncthreads();
    }
    if (i < NODES) {
        int excl = s[t] - v + boff[blockIdx.x];
        rowptr[i] = excl;
        cursor[i] = excl;
    }
    if (blockIdx.x == 0 && t == 0) rowptr[NODES] = EDGES;
}

__global__ __launch_bounds__(256) void fill_kernel(
    const int* __restrict__ src, const int* __restrict__ dst,
    int* __restrict__ cursor, int* __restrict__ csr)
{
    int e = blockIdx.x * 256 + threadIdx.x;
    if (e < EDGES) {
        int pos = atomicAdd(&cursor[dst[e]], 1);
        csr[pos] = src[e];
    }
}

// ---------------------------------------------------------------------------
// Weight prep: wt[m][n][k] = bf16(w[m][k][n]), m = 0..2 -> w1, 3..5 -> w2
// ---------------------------------------------------------------------------
__global__ __launch_bounds__(256) void prep_w_kernel(
    const float* __restrict__ w1, const float* __restrict__ w2,
    unsigned short* __restrict__ wt)
{
    int idx = blockIdx.x * 256 + threadIdx.x;
    if (idx >= 6 * HID * HID) return;
    int m = idx >> 14;
    int n = (idx >> 7) & 127;
    int k = idx & 127;
    const float* w = (m < 3) ? (w1 + (size_t)m * HID * HID)
                             : (w2 + (size_t)(m - 3) * HID * HID);
    wt[idx] = f2bf(w[(size_t)k * HID + n]);
}

// ---------------------------------------------------------------------------
// x f32 -> bf16 (packed pairs)
// ---------------------------------------------------------------------------
__global__ __launch_bounds__(256) void conv_kernel(
    const float* __restrict__ x, unsigned* __restrict__ xb)
{
    int i = blockIdx.x * 256 + threadIdx.x;   // pair index
    if (i >= NODES * 64) return;
    float2 v = reinterpret_cast<const float2*>(x)[i];
    xb[i] = ((unsigned)f2bf(v.y) << 16) | f2bf(v.x);
}

// ---------------------------------------------------------------------------
// Gather, 16 edges in flight: one wave per node, quarter-wave per neighbor
// row (16 lanes x dwordx4 = 256 B = full bf16 row), 4 unrolled per quarter.
// Branchless: clamp edge index, mask contribution.
// ---------------------------------------------------------------------------
__global__ __launch_bounds__(256) void gather4_kernel(
    const unsigned short* __restrict__ x,
    const int* __restrict__ rowptr, const int* __restrict__ csr,
    unsigned short* __restrict__ hin)
{
    const int w    = threadIdx.x >> 6;
    const int lane = threadIdx.x & 63;
    const int n    = blockIdx.x * 4 + w;
    if (n >= NODES) return;
    const int q  = lane >> 4;      // quarter 0..3 -> neighbor slot
    const int lr = lane & 15;      // 16B chunk within row

    const uint4* xr = reinterpret_cast<const uint4*>(x);   // 16 uint4 per row

    float acc[8];
    #pragma unroll
    for (int i = 0; i < 8; ++i) acc[i] = 0.f;

    const int lo = rowptr[n], hi = rowptr[n + 1];
    for (int e0 = lo; e0 < hi; e0 += 16) {
        uint4 v[4];
        unsigned m[4];
        #pragma unroll
        for (int j = 0; j < 4; ++j) {
            int e = e0 + 4 * j + q;
            bool ok = e < hi;
            m[j] = ok ? 0xffffffffu : 0u;
            int ec = ok ? e : (hi - 1);          // always-valid load address
            v[j] = xr[(size_t)csr[ec] * 16 + lr];
        }
        #pragma unroll
        for (int j = 0; j < 4; ++j) {
            const unsigned uu[4] = {v[j].x, v[j].y, v[j].z, v[j].w};
            #pragma unroll
            for (int k2 = 0; k2 < 4; ++k2) {
                unsigned uv = uu[k2] & m[j];
                acc[2 * k2]     += __uint_as_float(uv << 16);
                acc[2 * k2 + 1] += __uint_as_float(uv & 0xffff0000u);
            }
        }
    }

    #pragma unroll
    for (int i = 0; i < 8; ++i) {
        acc[i] += __shfl_xor(acc[i], 16, 64);
        acc[i] += __shfl_xor(acc[i], 32, 64);
    }

    if (q == 0) {
        uint4 self = xr[(size_t)n * 16 + lr];
        const unsigned su[4] = {self.x, self.y, self.z, self.w};
        uint4 o;
        unsigned* ou = &o.x;
        #pragma unroll
        for (int j = 0; j < 4; ++j) {
            float c0 = acc[2 * j]     + __uint_as_float(su[j] << 16);
            float c1 = acc[2 * j + 1] + __uint_as_float(su[j] & 0xffff0000u);
            ou[j] = ((unsigned)f2bf(c1) << 16) | f2bf(c0);
        }
        reinterpret_cast<uint4*>(hin)[(size_t)n * 16 + lr] = o;
    }
}

// ---------------------------------------------------------------------------
// Fused dual MFMA GEMM: C = relu( relu(A@W1+b1) @ W2 + b2 ), bf16 in/out.
// 128-row tile, 4 waves; each wave owns a 32-row stripe (2 row-sets of 16)
// sharing every W fragment across both row-sets (2x MFMA per W load, 16
// independent accumulation chains). h1 kept in wave-private LDS rows.
// ---------------------------------------------------------------------------
__global__ __launch_bounds__(256) void gemm_dual_kernel(
    const unsigned short* __restrict__ A,
    const unsigned short* __restrict__ Wt1, const float* __restrict__ bias1,
    const unsigned short* __restrict__ Wt2, const float* __restrict__ bias2,
    unsigned short* __restrict__ C,
    int M)
{
    __shared__ unsigned short As[128][136];
    const int tid  = threadIdx.x;
    const int row0 = blockIdx.x * 128;

    #pragma unroll
    for (int j = 0; j < 8; ++j) {
        int chunk = tid + 256 * j;          // 0..2047
        int r  = chunk >> 4;                // 0..127
        int cw = chunk & 15;
        int gr = row0 + r;
        uint4 v = make_uint4(0u, 0u, 0u, 0u);
        if (gr < M) v = *reinterpret_cast<const uint4*>(A + (size_t)gr * HID + cw * 8);
        *reinterpret_cast<uint4*>(&As[r][cw * 8]) = v;
    }
    __syncthreads();

    const int w    = tid >> 6;
    const int lane = tid & 63;
    const int lr   = lane & 15;
    const int lg   = lane >> 4;
    const int ar0  = w * 32 + lr;       // row-set 0
    const int ar1  = ar0 + 16;          // row-set 1

    bf16x8 af0[4], af1[4];
    f32x4 acc0[8], acc1[8];

    // ---- GEMM 1 ----
    #pragma unroll
    for (int s = 0; s < 4; ++s) {
        af0[s] = *reinterpret_cast<const bf16x8*>(&As[ar0][s * 32 + lg * 8]);
        af1[s] = *reinterpret_cast<const bf16x8*>(&As[ar1][s * 32 + lg * 8]);
    }
    #pragma unroll
    for (int nt = 0; nt < 8; ++nt) {
        acc0[nt] = (f32x4){0.f, 0.f, 0.f, 0.f};
        acc1[nt] = (f32x4){0.f, 0.f, 0.f, 0.f};
    }
    {
        const unsigned short* wp = Wt1 + (size_t)lr * HID + lg * 8;
        #pragma unroll
        for (int nt = 0; nt < 8; ++nt) {
            const unsigned short* wn = wp + (size_t)nt * 16 * HID;
            #pragma unroll
            for (int s = 0; s < 4; ++s) {
                bf16x8 b = *reinterpret_cast<const bf16x8*>(wn + s * 32);
                acc0[nt] = __builtin_amdgcn_mfma_f32_16x16x32_bf16(b, af0[s], acc0[nt], 0, 0, 0);
                acc1[nt] = __builtin_amdgcn_mfma_f32_16x16x32_bf16(b, af1[s], acc1[nt], 0, 0, 0);
            }
        }
    }

    // bias1 + relu -> h1 back into LDS (wave-private rows)
    {
        const float4* b4p = reinterpret_cast<const float4*>(bias1);
        #pragma unroll
        for (int nt = 0; nt < 8; ++nt) {
            float4 b4 = b4p[nt * 4 + lg];
            ushort4 o0, o1;
            o0.x = f2bf(fmaxf(acc0[nt][0] + b4.x, 0.f));
            o0.y = f2bf(fmaxf(acc0[nt][1] + b4.y, 0.f));
            o0.z = f2bf(fmaxf(acc0[nt][2] + b4.z, 0.f));
            o0.w = f2bf(fmaxf(acc0[nt][3] + b4.w, 0.f));
            o1.x = f2bf(fmaxf(acc1[nt][0] + b4.x, 0.f));
            o1.y = f2bf(fmaxf(acc1[nt][1] + b4.y, 0.f));
            o1.z = f2bf(fmaxf(acc1[nt][2] + b4.z, 0.f));
            o1.w = f2bf(fmaxf(acc1[nt][3] + b4.w, 0.f));
            *reinterpret_cast<ushort4*>(&As[ar0][nt * 16 + lg * 4]) = o0;
            *reinterpret_cast<ushort4*>(&As[ar1][nt * 16 + lg * 4]) = o1;
        }
    }

    // ---- GEMM 2 ----
    #pragma unroll
    for (int s = 0; s < 4; ++s) {
        af0[s] = *reinterpret_cast<const bf16x8*>(&As[ar0][s * 32 + lg * 8]);
        af1[s] = *reinterpret_cast<const bf16x8*>(&As[ar1][s * 32 + lg * 8]);
    }
    #pragma unroll
    for (int nt = 0; nt < 8; ++nt) {
        acc0[nt] = (f32x4){0.f, 0.f, 0.f, 0.f};
        acc1[nt] = (f32x4){0.f, 0.f, 0.f, 0.f};
    }
    {
        const unsigned short* wp = Wt2 + (size_t)lr * HID + lg * 8;
        #pragma unroll
        for (int nt = 0; nt < 8; ++nt) {
            const unsigned short* wn = wp + (size_t)nt * 16 * HID;
            #pragma unroll
            for (int s = 0; s < 4; ++s) {
                bf16x8 b = *reinterpret_cast<const bf16x8*>(wn + s * 32);
                acc0[nt] = __builtin_amdgcn_mfma_f32_16x16x32_bf16(b, af0[s], acc0[nt], 0, 0, 0);
                acc1[nt] = __builtin_amdgcn_mfma_f32_16x16x32_bf16(b, af1[s], acc1[nt], 0, 0, 0);
            }
        }
    }

    const int r0 = row0 + ar0;
    const int r1 = row0 + ar1;
    {
        const float4* b4p = reinterpret_cast<const float4*>(bias2);
        #pragma unroll
        for (int nt = 0; nt < 8; ++nt) {
            int col = nt * 16 + lg * 4;
            float4 b4 = b4p[nt * 4 + lg];
            if (r0 < M) {
                ushort4 o;
                o.x = f2bf(fmaxf(acc0[nt][0] + b4.x, 0.f));
                o.y = f2bf(fmaxf(acc0[nt][1] + b4.y, 0.f));
                o.z = f2bf(fmaxf(acc0[nt][2] + b4.z, 0.f));
                o.w = f2bf(fmaxf(acc0[nt][3] + b4.w, 0.f));
                *reinterpret_cast<ushort4*>(C + (size_t)r0 * HID + col) = o;
            }
            if (r1 < M) {
                ushort4 o;
                o.x = f2bf(fmaxf(acc1[nt][0] + b4.x, 0.f));
                o.y = f2bf(fmaxf(acc1[nt][1] + b4.y, 0.f));
                o.z = f2bf(fmaxf(acc1[nt][2] + b4.z, 0.f));
                o.w = f2bf(fmaxf(acc1[nt][3] + b4.w, 0.f));
                *reinterpret_cast<ushort4*>(C + (size_t)r1 * HID + col) = o;
            }
        }
    }
}

// ---------------------------------------------------------------------------
// Pool over sorted batch ids (bf16 in, f32 out)
// ---------------------------------------------------------------------------
__device__ __forceinline__ int lbound(const int* __restrict__ a, int v)
{
    int lo = 0, hi = NODES;
    while (lo < hi) {
        int m = (lo + hi) >> 1;
        if (a[m] < v) lo = m + 1; else hi = m;
    }
    return lo;
}

__global__ __launch_bounds__(256) void pool_sorted_kernel(
    const unsigned short* __restrict__ x,
    const int* __restrict__ batch,
    float* __restrict__ g)
{
    const int gid = blockIdx.x;
    const int beg = lbound(batch, gid);
    const int end = lbound(batch, gid + 1);

    const int c    = threadIdx.x & 127;
    const int half = threadIdx.x >> 7;

    float acc = 0.f;
    for (int r = beg + half; r < end; r += 2)
        acc += bf2f(x[(size_t)r * HID + c]);

    __shared__ float lds[256];
    lds[threadIdx.x] = acc;
    __syncthreads();
    if (threadIdx.x < 128)
        g[(size_t)gid * HID + threadIdx.x] = lds[threadIdx.x] + lds[threadIdx.x + 128];
}

// ---------------------------------------------------------------------------
// Small f32 GEMM for the graph-level MLP (M=500)
// ---------------------------------------------------------------------------
__global__ __launch_bounds__(256) void gemm128_f32_kernel(
    const float* __restrict__ A,
    const float* __restrict__ W,
    const float* __restrict__ bias,
    float* __restrict__ C,
    int M)
{
    __shared__ float As[32][HID];
    const int tid  = threadIdx.x;
    const int row0 = blockIdx.x * 32;

    {
        const int r = tid >> 3;
        const int c = (tid & 7) * 16;
        const int gr = row0 + r;
        float4* ps = reinterpret_cast<float4*>(&As[r][c]);
        if (gr < M) {
            const float4* pa = reinterpret_cast<const float4*>(A + (size_t)gr * HID + c);
            #pragma unroll
            for (int j = 0; j < 4; ++j) ps[j] = pa[j];
        } else {
            #pragma unroll
            for (int j = 0; j < 4; ++j) ps[j] = make_float4(0.f, 0.f, 0.f, 0.f);
        }
    }
    __syncthreads();

    const int tx = tid & 31;
    const int ty = tid >> 5;

    float4 acc[4];
    #pragma unroll
    for (int i = 0; i < 4; ++i) acc[i] = make_float4(0.f, 0.f, 0.f, 0.f);

    #pragma unroll 4
    for (int k = 0; k < HID; ++k) {
        const float4 w = *reinterpret_cast<const float4*>(W + (size_t)k * HID + tx * 4);
        #pragma unroll
        for (int i = 0; i < 4; ++i) {
            const float a = As[ty + 8 * i][k];
            acc[i].x += a * w.x;
            acc[i].y += a * w.y;
            acc[i].z += a * w.z;
            acc[i].w += a * w.w;
        }
    }

    const float4 b4 = *reinterpret_cast<const float4*>(bias + tx * 4);
    #pragma unroll
    for (int i = 0; i < 4; ++i) {
        const int row = row0 + ty + 8 * i;
        if (row < M) {
            float4 o = make_float4(fmaxf(acc[i].x + b4.x, 0.f),
                                   fmaxf(acc[i].y + b4.y, 0.f),
                                   fmaxf(acc[i].z + b4.z, 0.f),
                                   fmaxf(acc[i].w + b4.w, 0.f));
            *reinterpret_cast<float4*>(C + (size_t)row * HID + tx * 4) = o;
        }
    }
}

__global__ __launch_bounds__(256) void final_kernel(
    const float* __restrict__ gh,
    const float* __restrict__ w2,
    const float* __restrict__ b2,
    float* __restrict__ out)
{
    int idx = blockIdx.x * 256 + threadIdx.x;
    int r = idx >> 4;
    int c = idx & 15;
    if (r >= GRAPHS || c >= OUTC) return;
    float acc = b2[c];
    for (int k = 0; k < HID; ++k)
        acc += gh[(size_t)r * HID + k] * w2[(size_t)k * OUTC + c];
    out[(size_t)r * OUTC + c] = acc;
}

// ---------------------------------------------------------------------------
extern "C" void kernel_launch(void* const* d_in, const int* in_sizes, int n_in,
                              void* d_out, int out_size, void* d_ws, size_t ws_size,
                              hipStream_t stream)
{
    const float* x    = (const float*)d_in[0];
    const float* w1   = (const float*)d_in[1];
    const float* b1   = (const float*)d_in[2];
    const float* w2   = (const float*)d_in[3];
    const float* b2   = (const float*)d_in[4];
    const float* mw1  = (const float*)d_in[5];
    const float* mb1  = (const float*)d_in[6];
    const float* mw2  = (const float*)d_in[7];
    const float* mb2  = (const float*)d_in[8];
    const int*   ei   = (const int*)d_in[9];
    const int*   batch= (const int*)d_in[10];
    float* out = (float*)d_out;

    // workspace layout
    char* p = (char*)d_ws;
    unsigned short* bufB = (unsigned short*)p;  p += (size_t)NODES * HID * 2;
    unsigned short* t0   = (unsigned short*)p;  p += (size_t)NODES * HID * 2;
    unsigned short* wt   = (unsigned short*)p;  p += (size_t)6 * HID * HID * 2;
    float* g      = (float*)p;                  p += (size_t)GRAPHS * HID * 4;
    float* gh     = (float*)p;                  p += (size_t)GRAPHS * HID * 4;
    int*   cursor = (int*)p;                    p += (size_t)NODES * 4;
    int*   rowptr = (int*)p;                    p += (size_t)(NODES + 1) * 4;
    int*   csr    = (int*)p;                    p += (size_t)EDGES * 4;
    int*   bsum   = (int*)p;                    p += 256 * 4;
    int*   boff   = (int*)p;

    const int* src = ei;
    const int* dst = ei + EDGES;

    const dim3 blk(256);
    const int edgeBlocks   = (EDGES + 255) / 256;       // 3125
    const int scanBlocks   = (NODES + 255) / 256;       // 196
    const int gatherBlocks = (NODES + 3) / 4;           // 12500
    const int gemmBlocks   = (NODES + 127) / 128;       // 391
    const int convBlocks   = (NODES * 64 + 255) / 256;  // 12500

    // ---- CSR build + weight/x prep ----
    hipMemsetAsync(cursor, 0, (size_t)NODES * sizeof(int), stream);
    degree_kernel<<<edgeBlocks, blk, 0, stream>>>(dst, cursor);
    scan_partial_kernel<<<scanBlocks, blk, 0, stream>>>(cursor, bsum);
    scan_small_kernel<<<1, blk, 0, stream>>>(bsum, boff);
    scan_final_kernel<<<scanBlocks, blk, 0, stream>>>(cursor, boff, rowptr);
    fill_kernel<<<edgeBlocks, blk, 0, stream>>>(src, dst, cursor, csr);
    prep_w_kernel<<<(6 * HID * HID + 255) / 256, blk, 0, stream>>>(w1, w2, wt);
    conv_kernel<<<convBlocks, blk, 0, stream>>>(x, (unsigned*)bufB);

    // ---- 3 GIN layers: gather(bufB->t0); dual-gemm(t0->bufB) ----
    for (int l = 0; l < NLAYERS; ++l) {
        gather4_kernel<<<gatherBlocks, blk, 0, stream>>>(bufB, rowptr, csr, t0);
        gemm_dual_kernel<<<gemmBlocks, blk, 0, stream>>>(
            t0,
            wt + (size_t)l * HID * HID,       b1 + (size_t)l * HID,
            wt + (size_t)(l + 3) * HID * HID, b2 + (size_t)l * HID,
            bufB, NODES);
    }

    // ---- pool + MLP ----
    pool_sorted_kernel<<<GRAPHS, blk, 0, stream>>>(bufB, batch, g);
    gemm128_f32_kernel<<<(GRAPHS + 31) / 32, blk, 0, stream>>>(g, mw1, mb1, gh, GRAPHS);
    final_kernel<<<(GRAPHS * 16 + 255) / 256, blk, 0, stream>>>(gh, mw2, mb2, out);
}

// Round 7
// 324.276 us; speedup vs baseline: 1.5175x; 1.0066x over previous
//
#include <hip/hip_runtime.h>

#define NODES   50000
#define EDGES   800000
#define GRAPHS  500
#define HID     128
#define OUTC    10
#define NLAYERS 3
#define ELLCAP  64

typedef __bf16 bf16x8 __attribute__((ext_vector_type(8)));
typedef float  f32x4  __attribute__((ext_vector_type(4)));

__device__ __forceinline__ unsigned short f2bf(float f){
    unsigned u = __float_as_uint(f);
    u = (u + 0x7fffu + ((u >> 16) & 1u)) >> 16;
    return (unsigned short)u;
}
__device__ __forceinline__ float bf2f(unsigned short h){
    return __uint_as_float(((unsigned)h) << 16);
}

// ---------------------------------------------------------------------------
// ELL build: one pass. deg must be zeroed. src fits in ushort (NODES < 65536).
// ---------------------------------------------------------------------------
__global__ __launch_bounds__(256) void fill_ell_kernel(
    const int* __restrict__ src, const int* __restrict__ dst,
    int* __restrict__ deg, unsigned short* __restrict__ ell)
{
    int e = blockIdx.x * 256 + threadIdx.x;
    if (e < EDGES) {
        int d = dst[e];
        int pos = atomicAdd(&deg[d], 1);
        if (pos < ELLCAP) ell[(size_t)d * ELLCAP + pos] = (unsigned short)src[e];
    }
}

// ---------------------------------------------------------------------------
// Weight prep: wt[m][n][k] = bf16(w[m][k][n]), m = 0..2 -> w1, 3..5 -> w2
// ---------------------------------------------------------------------------
__global__ __launch_bounds__(256) void prep_w_kernel(
    const float* __restrict__ w1, const float* __restrict__ w2,
    unsigned short* __restrict__ wt)
{
    int idx = blockIdx.x * 256 + threadIdx.x;
    if (idx >= 6 * HID * HID) return;
    int m = idx >> 14;
    int n = (idx >> 7) & 127;
    int k = idx & 127;
    const float* w = (m < 3) ? (w1 + (size_t)m * HID * HID)
                             : (w2 + (size_t)(m - 3) * HID * HID);
    wt[idx] = f2bf(w[(size_t)k * HID + n]);
}

// ---------------------------------------------------------------------------
// x f32 -> bf16 (packed pairs)
// ---------------------------------------------------------------------------
__global__ __launch_bounds__(256) void conv_kernel(
    const float* __restrict__ x, unsigned* __restrict__ xb)
{
    int i = blockIdx.x * 256 + threadIdx.x;   // pair index
    if (i >= NODES * 64) return;
    float2 v = reinterpret_cast<const float2*>(x)[i];
    xb[i] = ((unsigned)f2bf(v.y) << 16) | f2bf(v.x);
}

// ---------------------------------------------------------------------------
// Gather from ELL, 16 edges in flight: one wave per node, quarter-wave per
// neighbor row (16 lanes x dwordx4 = 256 B bf16 row), 4 unrolled per quarter.
// ---------------------------------------------------------------------------
__global__ __launch_bounds__(256) void gather_ell_kernel(
    const unsigned short* __restrict__ x,
    const int* __restrict__ deg, const unsigned short* __restrict__ ell,
    unsigned short* __restrict__ hin)
{
    const int w    = threadIdx.x >> 6;
    const int lane = threadIdx.x & 63;
    const int n    = blockIdx.x * 4 + w;
    if (n >= NODES) return;
    const int q  = lane >> 4;      // quarter 0..3 -> neighbor slot
    const int lr = lane & 15;      // 16B chunk within row

    const uint4* xr = reinterpret_cast<const uint4*>(x);   // 16 uint4 per row
    const unsigned short* nb = ell + (size_t)n * ELLCAP;

    float acc[8];
    #pragma unroll
    for (int i = 0; i < 8; ++i) acc[i] = 0.f;

    const int dg = min(deg[n], ELLCAP);
    for (int e0 = 0; e0 < dg; e0 += 16) {
        uint4 v[4];
        unsigned m[4];
        #pragma unroll
        for (int j = 0; j < 4; ++j) {
            int e = e0 + 4 * j + q;
            bool ok = e < dg;
            m[j] = ok ? 0xffffffffu : 0u;
            int ec = ok ? e : (dg - 1);          // always-valid entry
            v[j] = xr[(size_t)nb[ec] * 16 + lr];
        }
        #pragma unroll
        for (int j = 0; j < 4; ++j) {
            const unsigned uu[4] = {v[j].x, v[j].y, v[j].z, v[j].w};
            #pragma unroll
            for (int k2 = 0; k2 < 4; ++k2) {
                unsigned uv = uu[k2] & m[j];
                acc[2 * k2]     += __uint_as_float(uv << 16);
                acc[2 * k2 + 1] += __uint_as_float(uv & 0xffff0000u);
            }
        }
    }

    #pragma unroll
    for (int i = 0; i < 8; ++i) {
        acc[i] += __shfl_xor(acc[i], 16, 64);
        acc[i] += __shfl_xor(acc[i], 32, 64);
    }

    if (q == 0) {
        uint4 self = xr[(size_t)n * 16 + lr];
        const unsigned su[4] = {self.x, self.y, self.z, self.w};
        uint4 o;
        unsigned* ou = &o.x;
        #pragma unroll
        for (int j = 0; j < 4; ++j) {
            float c0 = acc[2 * j]     + __uint_as_float(su[j] << 16);
            float c1 = acc[2 * j + 1] + __uint_as_float(su[j] & 0xffff0000u);
            ou[j] = ((unsigned)f2bf(c1) << 16) | f2bf(c0);
        }
        reinterpret_cast<uint4*>(hin)[(size_t)n * 16 + lr] = o;
    }
}

// ---------------------------------------------------------------------------
// Fused dual MFMA GEMM: C = relu( relu(A@W1+b1) @ W2 + b2 ), bf16 in/out.
// 128-row tile, 512 threads (8 waves x 16 rows) for 3 waves/SIMD occupancy.
// h1 kept in wave-private LDS rows (no barrier between the two GEMMs).
// ---------------------------------------------------------------------------
__global__ __launch_bounds__(512) void gemm_dual_kernel(
    const unsigned short* __restrict__ A,
    const unsigned short* __restrict__ Wt1, const float* __restrict__ bias1,
    const unsigned short* __restrict__ Wt2, const float* __restrict__ bias2,
    unsigned short* __restrict__ C,
    int M)
{
    __shared__ unsigned short As[128][136];
    const int tid  = threadIdx.x;
    const int row0 = blockIdx.x * 128;

    #pragma unroll
    for (int j = 0; j < 4; ++j) {
        int chunk = tid + 512 * j;          // 0..2047
        int r  = chunk >> 4;                // 0..127
        int cw = chunk & 15;
        int gr = row0 + r;
        uint4 v = make_uint4(0u, 0u, 0u, 0u);
        if (gr < M) v = *reinterpret_cast<const uint4*>(A + (size_t)gr * HID + cw * 8);
        *reinterpret_cast<uint4*>(&As[r][cw * 8]) = v;
    }
    __syncthreads();

    const int w    = tid >> 6;          // 0..7
    const int lane = tid & 63;
    const int lr   = lane & 15;
    const int lg   = lane >> 4;
    const int ar   = w * 16 + lr;       // this wave's row

    bf16x8 af[4];
    f32x4 acc[8];

    // ---- GEMM 1 ----
    #pragma unroll
    for (int s = 0; s < 4; ++s)
        af[s] = *reinterpret_cast<const bf16x8*>(&As[ar][s * 32 + lg * 8]);
    #pragma unroll
    for (int nt = 0; nt < 8; ++nt) acc[nt] = (f32x4){0.f, 0.f, 0.f, 0.f};
    {
        const unsigned short* wp = Wt1 + (size_t)lr * HID + lg * 8;
        #pragma unroll
        for (int nt = 0; nt < 8; ++nt) {
            const unsigned short* wn = wp + (size_t)nt * 16 * HID;
            #pragma unroll
            for (int s = 0; s < 4; ++s) {
                bf16x8 b = *reinterpret_cast<const bf16x8*>(wn + s * 32);
                acc[nt] = __builtin_amdgcn_mfma_f32_16x16x32_bf16(b, af[s], acc[nt], 0, 0, 0);
            }
        }
    }

    // bias1 + relu -> h1 back into LDS (wave-private rows)
    {
        const float4* b4p = reinterpret_cast<const float4*>(bias1);
        #pragma unroll
        for (int nt = 0; nt < 8; ++nt) {
            float4 b4 = b4p[nt * 4 + lg];
            ushort4 o;
            o.x = f2bf(fmaxf(acc[nt][0] + b4.x, 0.f));
            o.y = f2bf(fmaxf(acc[nt][1] + b4.y, 0.f));
            o.z = f2bf(fmaxf(acc[nt][2] + b4.z, 0.f));
            o.w = f2bf(fmaxf(acc[nt][3] + b4.w, 0.f));
            *reinterpret_cast<ushort4*>(&As[ar][nt * 16 + lg * 4]) = o;
        }
    }

    // ---- GEMM 2 ----
    #pragma unroll
    for (int s = 0; s < 4; ++s)
        af[s] = *reinterpret_cast<const bf16x8*>(&As[ar][s * 32 + lg * 8]);
    #pragma unroll
    for (int nt = 0; nt < 8; ++nt) acc[nt] = (f32x4){0.f, 0.f, 0.f, 0.f};
    {
        const unsigned short* wp = Wt2 + (size_t)lr * HID + lg * 8;
        #pragma unroll
        for (int nt = 0; nt < 8; ++nt) {
            const unsigned short* wn = wp + (size_t)nt * 16 * HID;
            #pragma unroll
            for (int s = 0; s < 4; ++s) {
                bf16x8 b = *reinterpret_cast<const bf16x8*>(wn + s * 32);
                acc[nt] = __builtin_amdgcn_mfma_f32_16x16x32_bf16(b, af[s], acc[nt], 0, 0, 0);
            }
        }
    }

    const int row = row0 + ar;
    if (row < M) {
        const float4* b4p = reinterpret_cast<const float4*>(bias2);
        #pragma unroll
        for (int nt = 0; nt < 8; ++nt) {
            int col = nt * 16 + lg * 4;
            float4 b4 = b4p[nt * 4 + lg];
            ushort4 o;
            o.x = f2bf(fmaxf(acc[nt][0] + b4.x, 0.f));
            o.y = f2bf(fmaxf(acc[nt][1] + b4.y, 0.f));
            o.z = f2bf(fmaxf(acc[nt][2] + b4.z, 0.f));
            o.w = f2bf(fmaxf(acc[nt][3] + b4.w, 0.f));
            *reinterpret_cast<ushort4*>(C + (size_t)row * HID + col) = o;
        }
    }
}

// ---------------------------------------------------------------------------
// Pool over sorted batch ids (bf16 in, f32 out)
// ---------------------------------------------------------------------------
__device__ __forceinline__ int lbound(const int* __restrict__ a, int v)
{
    int lo = 0, hi = NODES;
    while (lo < hi) {
        int m = (lo + hi) >> 1;
        if (a[m] < v) lo = m + 1; else hi = m;
    }
    return lo;
}

__global__ __launch_bounds__(256) void pool_sorted_kernel(
    const unsigned short* __restrict__ x,
    const int* __restrict__ batch,
    float* __restrict__ g)
{
    const int gid = blockIdx.x;
    const int beg = lbound(batch, gid);
    const int end = lbound(batch, gid + 1);

    const int c    = threadIdx.x & 127;
    const int half = threadIdx.x >> 7;

    float acc = 0.f;
    for (int r = beg + half; r < end; r += 2)
        acc += bf2f(x[(size_t)r * HID + c]);

    __shared__ float lds[256];
    lds[threadIdx.x] = acc;
    __syncthreads();
    if (threadIdx.x < 128)
        g[(size_t)gid * HID + threadIdx.x] = lds[threadIdx.x] + lds[threadIdx.x + 128];
}

// ---------------------------------------------------------------------------
// Small f32 GEMM for the graph-level MLP (M=500)
// ---------------------------------------------------------------------------
__global__ __launch_bounds__(256) void gemm128_f32_kernel(
    const float* __restrict__ A,
    const float* __restrict__ W,
    const float* __restrict__ bias,
    float* __restrict__ C,
    int M)
{
    __shared__ float As[32][HID];
    const int tid  = threadIdx.x;
    const int row0 = blockIdx.x * 32;

    {
        const int r = tid >> 3;
        const int c = (tid & 7) * 16;
        const int gr = row0 + r;
        float4* ps = reinterpret_cast<float4*>(&As[r][c]);
        if (gr < M) {
            const float4* pa = reinterpret_cast<const float4*>(A + (size_t)gr * HID + c);
            #pragma unroll
            for (int j = 0; j < 4; ++j) ps[j] = pa[j];
        } else {
            #pragma unroll
            for (int j = 0; j < 4; ++j) ps[j] = make_float4(0.f, 0.f, 0.f, 0.f);
        }
    }
    __syncthreads();

    const int tx = tid & 31;
    const int ty = tid >> 5;

    float4 acc[4];
    #pragma unroll
    for (int i = 0; i < 4; ++i) acc[i] = make_float4(0.f, 0.f, 0.f, 0.f);

    #pragma unroll 4
    for (int k = 0; k < HID; ++k) {
        const float4 w = *reinterpret_cast<const float4*>(W + (size_t)k * HID + tx * 4);
        #pragma unroll
        for (int i = 0; i < 4; ++i) {
            const float a = As[ty + 8 * i][k];
            acc[i].x += a * w.x;
            acc[i].y += a * w.y;
            acc[i].z += a * w.z;
            acc[i].w += a * w.w;
        }
    }

    const float4 b4 = *reinterpret_cast<const float4*>(bias + tx * 4);
    #pragma unroll
    for (int i = 0; i < 4; ++i) {
        const int row = row0 + ty + 8 * i;
        if (row < M) {
            float4 o = make_float4(fmaxf(acc[i].x + b4.x, 0.f),
                                   fmaxf(acc[i].y + b4.y, 0.f),
                                   fmaxf(acc[i].z + b4.z, 0.f),
                                   fmaxf(acc[i].w + b4.w, 0.f));
            *reinterpret_cast<float4*>(C + (size_t)row * HID + tx * 4) = o;
        }
    }
}

__global__ __launch_bounds__(256) void final_kernel(
    const float* __restrict__ gh,
    const float* __restrict__ w2,
    const float* __restrict__ b2,
    float* __restrict__ out)
{
    int idx = blockIdx.x * 256 + threadIdx.x;
    int r = idx >> 4;
    int c = idx & 15;
    if (r >= GRAPHS || c >= OUTC) return;
    float acc = b2[c];
    for (int k = 0; k < HID; ++k)
        acc += gh[(size_t)r * HID + k] * w2[(size_t)k * OUTC + c];
    out[(size_t)r * OUTC + c] = acc;
}

// ---------------------------------------------------------------------------
extern "C" void kernel_launch(void* const* d_in, const int* in_sizes, int n_in,
                              void* d_out, int out_size, void* d_ws, size_t ws_size,
                              hipStream_t stream)
{
    const float* x    = (const float*)d_in[0];
    const float* w1   = (const float*)d_in[1];
    const float* b1   = (const float*)d_in[2];
    const float* w2   = (const float*)d_in[3];
    const float* b2   = (const float*)d_in[4];
    const float* mw1  = (const float*)d_in[5];
    const float* mb1  = (const float*)d_in[6];
    const float* mw2  = (const float*)d_in[7];
    const float* mb2  = (const float*)d_in[8];
    const int*   ei   = (const int*)d_in[9];
    const int*   batch= (const int*)d_in[10];
    float* out = (float*)d_out;

    // workspace layout
    char* p = (char*)d_ws;
    unsigned short* bufB = (unsigned short*)p;  p += (size_t)NODES * HID * 2;
    unsigned short* t0   = (unsigned short*)p;  p += (size_t)NODES * HID * 2;
    unsigned short* ell  = (unsigned short*)p;  p += (size_t)NODES * ELLCAP * 2;
    unsigned short* wt   = (unsigned short*)p;  p += (size_t)6 * HID * HID * 2;
    float* g      = (float*)p;                  p += (size_t)GRAPHS * HID * 4;
    float* gh     = (float*)p;                  p += (size_t)GRAPHS * HID * 4;
    int*   deg    = (int*)p;                    p += (size_t)NODES * 4;

    const int* src = ei;
    const int* dst = ei + EDGES;

    const dim3 blk(256);
    const int edgeBlocks   = (EDGES + 255) / 256;       // 3125
    const int gatherBlocks = (NODES + 3) / 4;           // 12500
    const int gemmBlocks   = (NODES + 127) / 128;       // 391
    const int convBlocks   = (NODES * 64 + 255) / 256;  // 12500

    // ---- ELL build + weight/x prep ----
    hipMemsetAsync(deg, 0, (size_t)NODES * sizeof(int), stream);
    fill_ell_kernel<<<edgeBlocks, blk, 0, stream>>>(src, dst, deg, ell);
    prep_w_kernel<<<(6 * HID * HID + 255) / 256, blk, 0, stream>>>(w1, w2, wt);
    conv_kernel<<<convBlocks, blk, 0, stream>>>(x, (unsigned*)bufB);

    // ---- 3 GIN layers: gather(bufB->t0); dual-gemm(t0->bufB) ----
    for (int l = 0; l < NLAYERS; ++l) {
        gather_ell_kernel<<<gatherBlocks, blk, 0, stream>>>(bufB, deg, ell, t0);
        gemm_dual_kernel<<<gemmBlocks, dim3(512), 0, stream>>>(
            t0,
            wt + (size_t)l * HID * HID,       b1 + (size_t)l * HID,
            wt + (size_t)(l + 3) * HID * HID, b2 + (size_t)l * HID,
            bufB, NODES);
    }

    // ---- pool + MLP ----
    pool_sorted_kernel<<<GRAPHS, blk, 0, stream>>>(bufB, batch, g);
    gemm128_f32_kernel<<<(GRAPHS + 31) / 32, blk, 0, stream>>>(g, mw1, mb1, gh, GRAPHS);
    final_kernel<<<(GRAPHS * 16 + 255) / 256, blk, 0, stream>>>(gh, mw2, mb2, out);
}

// Round 8
// 302.365 us; speedup vs baseline: 1.6275x; 1.0725x over previous
//
#include <hip/hip_runtime.h>

#define NODES   50000
#define EDGES   800000
#define GRAPHS  500
#define HID     128
#define OUTC    10
#define NLAYERS 3
#define ELLCAP  64

typedef __bf16 bf16x8 __attribute__((ext_vector_type(8)));
typedef float  f32x4  __attribute__((ext_vector_type(4)));

__device__ __forceinline__ unsigned short f2bf(float f){
    unsigned u = __float_as_uint(f);
    u = (u + 0x7fffu + ((u >> 16) & 1u)) >> 16;
    return (unsigned short)u;
}
__device__ __forceinline__ float bf2f(unsigned short h){
    return __uint_as_float(((unsigned)h) << 16);
}

#define FILLB  ((EDGES + 255) / 256)            // 3125
#define PREPB  ((6 * HID * HID + 255) / 256)    // 384
#define CONVB  ((NODES * 64 + 255) / 256)       // 12500

// ---------------------------------------------------------------------------
// Fused setup: [0,FILLB) transposed-ELL fill; [FILLB,FILLB+PREPB) weight
// transpose+bf16; rest: x -> bf16. Independent work co-scheduled so the
// BW-bound conv hides under the latency-bound fill.
// ell layout: ell[slot][node] (slot-major) -> scatter stays L2-resident.
// ---------------------------------------------------------------------------
__global__ __launch_bounds__(256) void setup_kernel(
    const int* __restrict__ src, const int* __restrict__ dst,
    int* __restrict__ deg, unsigned short* __restrict__ ell,
    const float* __restrict__ w1, const float* __restrict__ w2,
    unsigned short* __restrict__ wt,
    const float* __restrict__ x, unsigned* __restrict__ xb)
{
    const int b = blockIdx.x;
    if (b < FILLB) {
        int e = b * 256 + threadIdx.x;
        if (e < EDGES) {
            int d = dst[e];
            int pos = atomicAdd(&deg[d], 1);
            if (pos < ELLCAP)
                ell[(size_t)pos * NODES + d] = (unsigned short)src[e];
        }
    } else if (b < FILLB + PREPB) {
        int idx = (b - FILLB) * 256 + threadIdx.x;
        if (idx < 6 * HID * HID) {
            int m = idx >> 14;
            int n = (idx >> 7) & 127;
            int k = idx & 127;
            const float* w = (m < 3) ? (w1 + (size_t)m * HID * HID)
                                     : (w2 + (size_t)(m - 3) * HID * HID);
            wt[idx] = f2bf(w[(size_t)k * HID + n]);
        }
    } else {
        int i = (b - FILLB - PREPB) * 256 + threadIdx.x;   // f32 pair index
        if (i < NODES * 64) {
            float2 v = reinterpret_cast<const float2*>(x)[i];
            xb[i] = ((unsigned)f2bf(v.y) << 16) | f2bf(v.x);
        }
    }
}

// ---------------------------------------------------------------------------
// Fused GIN layer: per 128-node tile, each wave (8/block) gathers its own 16
// node rows (quarter-wave per neighbor, 16 edges in flight) into its private
// LDS stripe, then computes C = relu( relu(hin@W1+b1) @ W2 + b2 ).
// Zero barriers: no cross-wave LDS sharing anywhere.
// ---------------------------------------------------------------------------
__global__ __launch_bounds__(512) void layer_kernel(
    const unsigned short* __restrict__ X,
    const int* __restrict__ deg, const unsigned short* __restrict__ ell,
    const unsigned short* __restrict__ Wt1, const float* __restrict__ bias1,
    const unsigned short* __restrict__ Wt2, const float* __restrict__ bias2,
    unsigned short* __restrict__ C)
{
    __shared__ unsigned short As[128][136];
    const int tid  = threadIdx.x;
    const int w    = tid >> 6;          // wave 0..7
    const int lane = tid & 63;
    const int q    = lane >> 4;         // quarter -> neighbor slot
    const int lr   = lane & 15;         // 16B chunk within row
    const int row0 = blockIdx.x * 128;

    const uint4* xr = reinterpret_cast<const uint4*>(X);   // 16 uint4 per row

    // ---- gather this wave's 16 rows ----
    for (int i = 0; i < 16; ++i) {
        const int row = w * 16 + i;
        int n = row0 + row;
        if (n >= NODES) n = NODES - 1;          // tail: redundant compute, store guarded

        float acc[8];
        #pragma unroll
        for (int k = 0; k < 8; ++k) acc[k] = 0.f;

        const int dg = min(deg[n], ELLCAP);
        for (int e0 = 0; e0 < dg; e0 += 16) {
            uint4 v[4];
            unsigned m[4];
            #pragma unroll
            for (int j = 0; j < 4; ++j) {
                int e = e0 + 4 * j + q;
                bool ok = e < dg;
                m[j] = ok ? 0xffffffffu : 0u;
                int ec = ok ? e : (dg - 1);
                int s = ell[(size_t)ec * NODES + n];
                v[j] = xr[(size_t)s * 16 + lr];
            }
            #pragma unroll
            for (int j = 0; j < 4; ++j) {
                const unsigned uu[4] = {v[j].x, v[j].y, v[j].z, v[j].w};
                #pragma unroll
                for (int k2 = 0; k2 < 4; ++k2) {
                    unsigned uv = uu[k2] & m[j];
                    acc[2 * k2]     += __uint_as_float(uv << 16);
                    acc[2 * k2 + 1] += __uint_as_float(uv & 0xffff0000u);
                }
            }
        }

        #pragma unroll
        for (int k = 0; k < 8; ++k) {
            acc[k] += __shfl_xor(acc[k], 16, 64);
            acc[k] += __shfl_xor(acc[k], 32, 64);
        }

        if (q == 0) {
            uint4 self = xr[(size_t)n * 16 + lr];
            const unsigned su[4] = {self.x, self.y, self.z, self.w};
            uint4 o;
            unsigned* ou = &o.x;
            #pragma unroll
            for (int j = 0; j < 4; ++j) {
                float c0 = acc[2 * j]     + __uint_as_float(su[j] << 16);
                float c1 = acc[2 * j + 1] + __uint_as_float(su[j] & 0xffff0000u);
                ou[j] = ((unsigned)f2bf(c1) << 16) | f2bf(c0);
            }
            *reinterpret_cast<uint4*>(&As[row][lr * 8]) = o;
        }
    }
    // wave-private rows: no __syncthreads needed (compiler orders LDS w/r)

    const int ar = w * 16 + lr;

    bf16x8 af[4];
    f32x4 acc[8];

    // ---- GEMM 1 ----
    #pragma unroll
    for (int s = 0; s < 4; ++s)
        af[s] = *reinterpret_cast<const bf16x8*>(&As[ar][s * 32 + (lane >> 4) * 8]);
    #pragma unroll
    for (int nt = 0; nt < 8; ++nt) acc[nt] = (f32x4){0.f, 0.f, 0.f, 0.f};
    {
        const unsigned short* wp = Wt1 + (size_t)lr * HID + q * 8;
        #pragma unroll
        for (int nt = 0; nt < 8; ++nt) {
            const unsigned short* wn = wp + (size_t)nt * 16 * HID;
            #pragma unroll
            for (int s = 0; s < 4; ++s) {
                bf16x8 b = *reinterpret_cast<const bf16x8*>(wn + s * 32);
                acc[nt] = __builtin_amdgcn_mfma_f32_16x16x32_bf16(b, af[s], acc[nt], 0, 0, 0);
            }
        }
    }

    // bias1 + relu -> h1 back into LDS (wave-private rows)
    {
        const float4* b4p = reinterpret_cast<const float4*>(bias1);
        #pragma unroll
        for (int nt = 0; nt < 8; ++nt) {
            float4 b4 = b4p[nt * 4 + q];
            ushort4 o;
            o.x = f2bf(fmaxf(acc[nt][0] + b4.x, 0.f));
            o.y = f2bf(fmaxf(acc[nt][1] + b4.y, 0.f));
            o.z = f2bf(fmaxf(acc[nt][2] + b4.z, 0.f));
            o.w = f2bf(fmaxf(acc[nt][3] + b4.w, 0.f));
            *reinterpret_cast<ushort4*>(&As[ar][nt * 16 + q * 4]) = o;
        }
    }

    // ---- GEMM 2 ----
    #pragma unroll
    for (int s = 0; s < 4; ++s)
        af[s] = *reinterpret_cast<const bf16x8*>(&As[ar][s * 32 + q * 8]);
    #pragma unroll
    for (int nt = 0; nt < 8; ++nt) acc[nt] = (f32x4){0.f, 0.f, 0.f, 0.f};
    {
        const unsigned short* wp = Wt2 + (size_t)lr * HID + q * 8;
        #pragma unroll
        for (int nt = 0; nt < 8; ++nt) {
            const unsigned short* wn = wp + (size_t)nt * 16 * HID;
            #pragma unroll
            for (int s = 0; s < 4; ++s) {
                bf16x8 b = *reinterpret_cast<const bf16x8*>(wn + s * 32);
                acc[nt] = __builtin_amdgcn_mfma_f32_16x16x32_bf16(b, af[s], acc[nt], 0, 0, 0);
            }
        }
    }

    const int row = row0 + ar;
    if (row < NODES) {
        const float4* b4p = reinterpret_cast<const float4*>(bias2);
        #pragma unroll
        for (int nt = 0; nt < 8; ++nt) {
            int col = nt * 16 + q * 4;
            float4 b4 = b4p[nt * 4 + q];
            ushort4 o;
            o.x = f2bf(fmaxf(acc[nt][0] + b4.x, 0.f));
            o.y = f2bf(fmaxf(acc[nt][1] + b4.y, 0.f));
            o.z = f2bf(fmaxf(acc[nt][2] + b4.z, 0.f));
            o.w = f2bf(fmaxf(acc[nt][3] + b4.w, 0.f));
            *reinterpret_cast<ushort4*>(C + (size_t)row * HID + col) = o;
        }
    }
}

// ---------------------------------------------------------------------------
// Pool over sorted batch ids (bf16 in, f32 out)
// ---------------------------------------------------------------------------
__device__ __forceinline__ int lbound(const int* __restrict__ a, int v)
{
    int lo = 0, hi = NODES;
    while (lo < hi) {
        int m = (lo + hi) >> 1;
        if (a[m] < v) lo = m + 1; else hi = m;
    }
    return lo;
}

__global__ __launch_bounds__(256) void pool_sorted_kernel(
    const unsigned short* __restrict__ x,
    const int* __restrict__ batch,
    float* __restrict__ g)
{
    const int gid = blockIdx.x;
    const int beg = lbound(batch, gid);
    const int end = lbound(batch, gid + 1);

    const int c    = threadIdx.x & 127;
    const int half = threadIdx.x >> 7;

    float acc = 0.f;
    for (int r = beg + half; r < end; r += 2)
        acc += bf2f(x[(size_t)r * HID + c]);

    __shared__ float lds[256];
    lds[threadIdx.x] = acc;
    __syncthreads();
    if (threadIdx.x < 128)
        g[(size_t)gid * HID + threadIdx.x] = lds[threadIdx.x] + lds[threadIdx.x + 128];
}

// ---------------------------------------------------------------------------
// Small f32 GEMM for the graph-level MLP (M=500)
// ---------------------------------------------------------------------------
__global__ __launch_bounds__(256) void gemm128_f32_kernel(
    const float* __restrict__ A,
    const float* __restrict__ W,
    const float* __restrict__ bias,
    float* __restrict__ C,
    int M)
{
    __shared__ float As[32][HID];
    const int tid  = threadIdx.x;
    const int row0 = blockIdx.x * 32;

    {
        const int r = tid >> 3;
        const int c = (tid & 7) * 16;
        const int gr = row0 + r;
        float4* ps = reinterpret_cast<float4*>(&As[r][c]);
        if (gr < M) {
            const float4* pa = reinterpret_cast<const float4*>(A + (size_t)gr * HID + c);
            #pragma unroll
            for (int j = 0; j < 4; ++j) ps[j] = pa[j];
        } else {
            #pragma unroll
            for (int j = 0; j < 4; ++j) ps[j] = make_float4(0.f, 0.f, 0.f, 0.f);
        }
    }
    __syncthreads();

    const int tx = tid & 31;
    const int ty = tid >> 5;

    float4 acc[4];
    #pragma unroll
    for (int i = 0; i < 4; ++i) acc[i] = make_float4(0.f, 0.f, 0.f, 0.f);

    #pragma unroll 4
    for (int k = 0; k < HID; ++k) {
        const float4 w = *reinterpret_cast<const float4*>(W + (size_t)k * HID + tx * 4);
        #pragma unroll
        for (int i = 0; i < 4; ++i) {
            const float a = As[ty + 8 * i][k];
            acc[i].x += a * w.x;
            acc[i].y += a * w.y;
            acc[i].z += a * w.z;
            acc[i].w += a * w.w;
        }
    }

    const float4 b4 = *reinterpret_cast<const float4*>(bias + tx * 4);
    #pragma unroll
    for (int i = 0; i < 4; ++i) {
        const int row = row0 + ty + 8 * i;
        if (row < M) {
            float4 o = make_float4(fmaxf(acc[i].x + b4.x, 0.f),
                                   fmaxf(acc[i].y + b4.y, 0.f),
                                   fmaxf(acc[i].z + b4.z, 0.f),
                                   fmaxf(acc[i].w + b4.w, 0.f));
            *reinterpret_cast<float4*>(C + (size_t)row * HID + tx * 4) = o;
        }
    }
}

__global__ __launch_bounds__(256) void final_kernel(
    const float* __restrict__ gh,
    const float* __restrict__ w2,
    const float* __restrict__ b2,
    float* __restrict__ out)
{
    int idx = blockIdx.x * 256 + threadIdx.x;
    int r = idx >> 4;
    int c = idx & 15;
    if (r >= GRAPHS || c >= OUTC) return;
    float acc = b2[c];
    for (int k = 0; k < HID; ++k)
        acc += gh[(size_t)r * HID + k] * w2[(size_t)k * OUTC + c];
    out[(size_t)r * OUTC + c] = acc;
}

// ---------------------------------------------------------------------------
extern "C" void kernel_launch(void* const* d_in, const int* in_sizes, int n_in,
                              void* d_out, int out_size, void* d_ws, size_t ws_size,
                              hipStream_t stream)
{
    const float* x    = (const float*)d_in[0];
    const float* w1   = (const float*)d_in[1];
    const float* b1   = (const float*)d_in[2];
    const float* w2   = (const float*)d_in[3];
    const float* b2   = (const float*)d_in[4];
    const float* mw1  = (const float*)d_in[5];
    const float* mb1  = (const float*)d_in[6];
    const float* mw2  = (const float*)d_in[7];
    const float* mb2  = (const float*)d_in[8];
    const int*   ei   = (const int*)d_in[9];
    const int*   batch= (const int*)d_in[10];
    float* out = (float*)d_out;

    // workspace layout
    char* p = (char*)d_ws;
    unsigned short* buf0 = (unsigned short*)p;  p += (size_t)NODES * HID * 2;
    unsigned short* buf1 = (unsigned short*)p;  p += (size_t)NODES * HID * 2;
    unsigned short* ell  = (unsigned short*)p;  p += (size_t)NODES * ELLCAP * 2;
    unsigned short* wt   = (unsigned short*)p;  p += (size_t)6 * HID * HID * 2;
    float* g      = (float*)p;                  p += (size_t)GRAPHS * HID * 4;
    float* gh     = (float*)p;                  p += (size_t)GRAPHS * HID * 4;
    int*   deg    = (int*)p;                    p += (size_t)NODES * 4;

    const int* src = ei;
    const int* dst = ei + EDGES;

    const int layerBlocks = (NODES + 127) / 128;        // 391
    const int setupBlocks = FILLB + PREPB + CONVB;      // 16009

    // ---- setup: ELL fill + weight prep + x->bf16, co-scheduled ----
    hipMemsetAsync(deg, 0, (size_t)NODES * sizeof(int), stream);
    setup_kernel<<<setupBlocks, 256, 0, stream>>>(
        src, dst, deg, ell, w1, w2, wt, x, (unsigned*)buf0);

    // ---- 3 fused GIN layers (gather + dual GEMM), ping-pong buf0/buf1 ----
    unsigned short* bin  = buf0;
    unsigned short* bout = buf1;
    for (int l = 0; l < NLAYERS; ++l) {
        layer_kernel<<<layerBlocks, 512, 0, stream>>>(
            bin, deg, ell,
            wt + (size_t)l * HID * HID,       b1 + (size_t)l * HID,
            wt + (size_t)(l + 3) * HID * HID, b2 + (size_t)l * HID,
            bout);
        unsigned short* t = bin; bin = bout; bout = t;
    }

    // ---- pool + MLP ----
    pool_sorted_kernel<<<GRAPHS, 256, 0, stream>>>(bin, batch, g);
    gemm128_f32_kernel<<<(GRAPHS + 31) / 32, 256, 0, stream>>>(g, mw1, mb1, gh, GRAPHS);
    final_kernel<<<(GRAPHS * 16 + 255) / 256, 256, 0, stream>>>(gh, mw2, mb2, out);
}

// Round 9
// 281.245 us; speedup vs baseline: 1.7497x; 1.0751x over previous
//
#include <hip/hip_runtime.h>

#define NODES   50000
#define EDGES   800000
#define GRAPHS  500
#define HID     128
#define OUTC    10
#define NLAYERS 3
#define ELLCAP  64

typedef __bf16 bf16x8 __attribute__((ext_vector_type(8)));
typedef float  f32x4  __attribute__((ext_vector_type(4)));

__device__ __forceinline__ unsigned short f2bf(float f){
    unsigned u = __float_as_uint(f);
    u = (u + 0x7fffu + ((u >> 16) & 1u)) >> 16;
    return (unsigned short)u;
}
__device__ __forceinline__ float bf2f(unsigned short h){
    return __uint_as_float(((unsigned)h) << 16);
}

#define FILLB  ((EDGES + 255) / 256)            // 3125
#define PREPB  ((6 * HID * HID + 255) / 256)    // 384
#define CONVB  ((NODES * 64 + 255) / 256)       // 12500

// ---------------------------------------------------------------------------
// Fused setup: transposed-ELL fill | weight transpose+bf16 | x->bf16.
// ell layout: ell[slot][node] (slot-major) -> scatter stays L2-resident.
// ---------------------------------------------------------------------------
__global__ __launch_bounds__(256) void setup_kernel(
    const int* __restrict__ src, const int* __restrict__ dst,
    int* __restrict__ deg, unsigned short* __restrict__ ell,
    const float* __restrict__ w1, const float* __restrict__ w2,
    unsigned short* __restrict__ wt,
    const float* __restrict__ x, unsigned* __restrict__ xb)
{
    const int b = blockIdx.x;
    if (b < FILLB) {
        int e = b * 256 + threadIdx.x;
        if (e < EDGES) {
            int d = dst[e];
            int pos = atomicAdd(&deg[d], 1);
            if (pos < ELLCAP)
                ell[(size_t)pos * NODES + d] = (unsigned short)src[e];
        }
    } else if (b < FILLB + PREPB) {
        int idx = (b - FILLB) * 256 + threadIdx.x;
        if (idx < 6 * HID * HID) {
            int m = idx >> 14;
            int n = (idx >> 7) & 127;
            int k = idx & 127;
            const float* w = (m < 3) ? (w1 + (size_t)m * HID * HID)
                                     : (w2 + (size_t)(m - 3) * HID * HID);
            wt[idx] = f2bf(w[(size_t)k * HID + n]);
        }
    } else {
        int i = (b - FILLB - PREPB) * 256 + threadIdx.x;   // f32 pair index
        if (i < NODES * 64) {
            float2 v = reinterpret_cast<const float2*>(x)[i];
            xb[i] = ((unsigned)f2bf(v.y) << 16) | f2bf(v.x);
        }
    }
}

// ---------------------------------------------------------------------------
// Fused GIN layer, 64-row tile, 512 threads (8 waves):
//   gather: wave w gathers rows w*8..w*8+7 (quarter-wave per neighbor,
//           16 edges in flight) -> LDS
//   GEMM:   wave w computes row-group (w>>1)*16 x col-half (w&1)*64
//           of  C = relu( relu(hin@W1+b1) @ W2 + b2 )
// 782 blocks x 8 waves = 6256 waves -> ~76% occupancy (vs 26% at 128-tile).
// ---------------------------------------------------------------------------
__global__ __launch_bounds__(512) void layer_kernel(
    const unsigned short* __restrict__ X,
    const int* __restrict__ deg, const unsigned short* __restrict__ ell,
    const unsigned short* __restrict__ Wt1, const float* __restrict__ bias1,
    const unsigned short* __restrict__ Wt2, const float* __restrict__ bias2,
    unsigned short* __restrict__ C)
{
    __shared__ unsigned short As[64][136];
    const int tid  = threadIdx.x;
    const int w    = tid >> 6;          // wave 0..7
    const int lane = tid & 63;
    const int q    = lane >> 4;         // quarter -> neighbor slot / k-chunk
    const int lr   = lane & 15;         // 16B chunk within row / mfma row
    const int row0 = blockIdx.x * 64;

    const uint4* xr = reinterpret_cast<const uint4*>(X);   // 16 uint4 per row

    // ---- gather: this wave's 8 rows ----
    for (int i = 0; i < 8; ++i) {
        const int row = w * 8 + i;
        int n = row0 + row;
        if (n >= NODES) n = NODES - 1;      // tail: redundant compute, store guarded

        float acc[8];
        #pragma unroll
        for (int k = 0; k < 8; ++k) acc[k] = 0.f;

        const int dg = min(deg[n], ELLCAP);
        for (int e0 = 0; e0 < dg; e0 += 16) {
            uint4 v[4];
            unsigned m[4];
            #pragma unroll
            for (int j = 0; j < 4; ++j) {
                int e = e0 + 4 * j + q;
                bool ok = e < dg;
                m[j] = ok ? 0xffffffffu : 0u;
                int ec = ok ? e : (dg - 1);
                int s = ell[(size_t)ec * NODES + n];
                v[j] = xr[(size_t)s * 16 + lr];
            }
            #pragma unroll
            for (int j = 0; j < 4; ++j) {
                const unsigned uu[4] = {v[j].x, v[j].y, v[j].z, v[j].w};
                #pragma unroll
                for (int k2 = 0; k2 < 4; ++k2) {
                    unsigned uv = uu[k2] & m[j];
                    acc[2 * k2]     += __uint_as_float(uv << 16);
                    acc[2 * k2 + 1] += __uint_as_float(uv & 0xffff0000u);
                }
            }
        }

        #pragma unroll
        for (int k = 0; k < 8; ++k) {
            acc[k] += __shfl_xor(acc[k], 16, 64);
            acc[k] += __shfl_xor(acc[k], 32, 64);
        }

        if (q == 0) {
            uint4 self = xr[(size_t)n * 16 + lr];
            const unsigned su[4] = {self.x, self.y, self.z, self.w};
            uint4 o;
            unsigned* ou = &o.x;
            #pragma unroll
            for (int j = 0; j < 4; ++j) {
                float c0 = acc[2 * j]     + __uint_as_float(su[j] << 16);
                float c1 = acc[2 * j + 1] + __uint_as_float(su[j] & 0xffff0000u);
                ou[j] = ((unsigned)f2bf(c1) << 16) | f2bf(c0);
            }
            *reinterpret_cast<uint4*>(&As[row][lr * 8]) = o;
        }
    }
    __syncthreads();

    const int rg = w >> 1;              // row-group 0..3
    const int ch = w & 1;               // col-half 0..1
    const int ar = rg * 16 + lr;        // this wave's mfma row in tile

    bf16x8 af[4];
    f32x4 acc[4];

    // ---- GEMM 1: h1[16 x 64-half] ----
    #pragma unroll
    for (int s = 0; s < 4; ++s)
        af[s] = *reinterpret_cast<const bf16x8*>(&As[ar][s * 32 + q * 8]);
    #pragma unroll
    for (int nt = 0; nt < 4; ++nt) acc[nt] = (f32x4){0.f, 0.f, 0.f, 0.f};
    {
        #pragma unroll
        for (int nt = 0; nt < 4; ++nt) {
            const unsigned short* wn = Wt1 + (size_t)(ch * 64 + nt * 16 + lr) * HID + q * 8;
            #pragma unroll
            for (int s = 0; s < 4; ++s) {
                bf16x8 b = *reinterpret_cast<const bf16x8*>(wn + s * 32);
                acc[nt] = __builtin_amdgcn_mfma_f32_16x16x32_bf16(b, af[s], acc[nt], 0, 0, 0);
            }
        }
    }

    // bias1 + relu -> h1 into LDS (own rows x own col-half)
    {
        const float4* b4p = reinterpret_cast<const float4*>(bias1);
        #pragma unroll
        for (int nt = 0; nt < 4; ++nt) {
            int col = ch * 64 + nt * 16 + q * 4;
            float4 b4 = b4p[col >> 2];
            ushort4 o;
            o.x = f2bf(fmaxf(acc[nt][0] + b4.x, 0.f));
            o.y = f2bf(fmaxf(acc[nt][1] + b4.y, 0.f));
            o.z = f2bf(fmaxf(acc[nt][2] + b4.z, 0.f));
            o.w = f2bf(fmaxf(acc[nt][3] + b4.w, 0.f));
            *reinterpret_cast<ushort4*>(&As[ar][col]) = o;
        }
    }
    __syncthreads();

    // ---- GEMM 2 ----
    #pragma unroll
    for (int s = 0; s < 4; ++s)
        af[s] = *reinterpret_cast<const bf16x8*>(&As[ar][s * 32 + q * 8]);
    #pragma unroll
    for (int nt = 0; nt < 4; ++nt) acc[nt] = (f32x4){0.f, 0.f, 0.f, 0.f};
    {
        #pragma unroll
        for (int nt = 0; nt < 4; ++nt) {
            const unsigned short* wn = Wt2 + (size_t)(ch * 64 + nt * 16 + lr) * HID + q * 8;
            #pragma unroll
            for (int s = 0; s < 4; ++s) {
                bf16x8 b = *reinterpret_cast<const bf16x8*>(wn + s * 32);
                acc[nt] = __builtin_amdgcn_mfma_f32_16x16x32_bf16(b, af[s], acc[nt], 0, 0, 0);
            }
        }
    }

    const int row = row0 + ar;
    if (row < NODES) {
        const float4* b4p = reinterpret_cast<const float4*>(bias2);
        #pragma unroll
        for (int nt = 0; nt < 4; ++nt) {
            int col = ch * 64 + nt * 16 + q * 4;
            float4 b4 = b4p[col >> 2];
            ushort4 o;
            o.x = f2bf(fmaxf(acc[nt][0] + b4.x, 0.f));
            o.y = f2bf(fmaxf(acc[nt][1] + b4.y, 0.f));
            o.z = f2bf(fmaxf(acc[nt][2] + b4.z, 0.f));
            o.w = f2bf(fmaxf(acc[nt][3] + b4.w, 0.f));
            *reinterpret_cast<ushort4*>(C + (size_t)row * HID + col) = o;
        }
    }
}

// ---------------------------------------------------------------------------
// Pool over sorted batch ids (bf16 in, f32 out)
// ---------------------------------------------------------------------------
__device__ __forceinline__ int lbound(const int* __restrict__ a, int v)
{
    int lo = 0, hi = NODES;
    while (lo < hi) {
        int m = (lo + hi) >> 1;
        if (a[m] < v) lo = m + 1; else hi = m;
    }
    return lo;
}

__global__ __launch_bounds__(256) void pool_sorted_kernel(
    const unsigned short* __restrict__ x,
    const int* __restrict__ batch,
    float* __restrict__ g)
{
    const int gid = blockIdx.x;
    const int beg = lbound(batch, gid);
    const int end = lbound(batch, gid + 1);

    const int c    = threadIdx.x & 127;
    const int half = threadIdx.x >> 7;

    float acc = 0.f;
    for (int r = beg + half; r < end; r += 2)
        acc += bf2f(x[(size_t)r * HID + c]);

    __shared__ float lds[256];
    lds[threadIdx.x] = acc;
    __syncthreads();
    if (threadIdx.x < 128)
        g[(size_t)gid * HID + threadIdx.x] = lds[threadIdx.x] + lds[threadIdx.x + 128];
}

// ---------------------------------------------------------------------------
// Small f32 GEMM for the graph-level MLP (M=500)
// ---------------------------------------------------------------------------
__global__ __launch_bounds__(256) void gemm128_f32_kernel(
    const float* __restrict__ A,
    const float* __restrict__ W,
    const float* __restrict__ bias,
    float* __restrict__ C,
    int M)
{
    __shared__ float As[32][HID];
    const int tid  = threadIdx.x;
    const int row0 = blockIdx.x * 32;

    {
        const int r = tid >> 3;
        const int c = (tid & 7) * 16;
        const int gr = row0 + r;
        float4* ps = reinterpret_cast<float4*>(&As[r][c]);
        if (gr < M) {
            const float4* pa = reinterpret_cast<const float4*>(A + (size_t)gr * HID + c);
            #pragma unroll
            for (int j = 0; j < 4; ++j) ps[j] = pa[j];
        } else {
            #pragma unroll
            for (int j = 0; j < 4; ++j) ps[j] = make_float4(0.f, 0.f, 0.f, 0.f);
        }
    }
    __syncthreads();

    const int tx = tid & 31;
    const int ty = tid >> 5;

    float4 acc[4];
    #pragma unroll
    for (int i = 0; i < 4; ++i) acc[i] = make_float4(0.f, 0.f, 0.f, 0.f);

    #pragma unroll 4
    for (int k = 0; k < HID; ++k) {
        const float4 w = *reinterpret_cast<const float4*>(W + (size_t)k * HID + tx * 4);
        #pragma unroll
        for (int i = 0; i < 4; ++i) {
            const float a = As[ty + 8 * i][k];
            acc[i].x += a * w.x;
            acc[i].y += a * w.y;
            acc[i].z += a * w.z;
            acc[i].w += a * w.w;
        }
    }

    const float4 b4 = *reinterpret_cast<const float4*>(bias + tx * 4);
    #pragma unroll
    for (int i = 0; i < 4; ++i) {
        const int row = row0 + ty + 8 * i;
        if (row < M) {
            float4 o = make_float4(fmaxf(acc[i].x + b4.x, 0.f),
                                   fmaxf(acc[i].y + b4.y, 0.f),
                                   fmaxf(acc[i].z + b4.z, 0.f),
                                   fmaxf(acc[i].w + b4.w, 0.f));
            *reinterpret_cast<float4*>(C + (size_t)row * HID + tx * 4) = o;
        }
    }
}

__global__ __launch_bounds__(256) void final_kernel(
    const float* __restrict__ gh,
    const float* __restrict__ w2,
    const float* __restrict__ b2,
    float* __restrict__ out)
{
    int idx = blockIdx.x * 256 + threadIdx.x;
    int r = idx >> 4;
    int c = idx & 15;
    if (r >= GRAPHS || c >= OUTC) return;
    float acc = b2[c];
    for (int k = 0; k < HID; ++k)
        acc += gh[(size_t)r * HID + k] * w2[(size_t)k * OUTC + c];
    out[(size_t)r * OUTC + c] = acc;
}

// ---------------------------------------------------------------------------
extern "C" void kernel_launch(void* const* d_in, const int* in_sizes, int n_in,
                              void* d_out, int out_size, void* d_ws, size_t ws_size,
                              hipStream_t stream)
{
    const float* x    = (const float*)d_in[0];
    const float* w1   = (const float*)d_in[1];
    const float* b1   = (const float*)d_in[2];
    const float* w2   = (const float*)d_in[3];
    const float* b2   = (const float*)d_in[4];
    const float* mw1  = (const float*)d_in[5];
    const float* mb1  = (const float*)d_in[6];
    const float* mw2  = (const float*)d_in[7];
    const float* mb2  = (const float*)d_in[8];
    const int*   ei   = (const int*)d_in[9];
    const int*   batch= (const int*)d_in[10];
    float* out = (float*)d_out;

    // workspace layout
    char* p = (char*)d_ws;
    unsigned short* buf0 = (unsigned short*)p;  p += (size_t)NODES * HID * 2;
    unsigned short* buf1 = (unsigned short*)p;  p += (size_t)NODES * HID * 2;
    unsigned short* ell  = (unsigned short*)p;  p += (size_t)NODES * ELLCAP * 2;
    unsigned short* wt   = (unsigned short*)p;  p += (size_t)6 * HID * HID * 2;
    float* g      = (float*)p;                  p += (size_t)GRAPHS * HID * 4;
    float* gh     = (float*)p;                  p += (size_t)GRAPHS * HID * 4;
    int*   deg    = (int*)p;                    p += (size_t)NODES * 4;

    const int* src = ei;
    const int* dst = ei + EDGES;

    const int layerBlocks = (NODES + 63) / 64;          // 782
    const int setupBlocks = FILLB + PREPB + CONVB;      // 16009

    // ---- setup: ELL fill + weight prep + x->bf16, co-scheduled ----
    hipMemsetAsync(deg, 0, (size_t)NODES * sizeof(int), stream);
    setup_kernel<<<setupBlocks, 256, 0, stream>>>(
        src, dst, deg, ell, w1, w2, wt, x, (unsigned*)buf0);

    // ---- 3 fused GIN layers (gather + dual GEMM), ping-pong buf0/buf1 ----
    unsigned short* bin  = buf0;
    unsigned short* bout = buf1;
    for (int l = 0; l < NLAYERS; ++l) {
        layer_kernel<<<layerBlocks, 512, 0, stream>>>(
            bin, deg, ell,
            wt + (size_t)l * HID * HID,       b1 + (size_t)l * HID,
            wt + (size_t)(l + 3) * HID * HID, b2 + (size_t)l * HID,
            bout);
        unsigned short* t = bin; bin = bout; bout = t;
    }

    // ---- pool + MLP ----
    pool_sorted_kernel<<<GRAPHS, 256, 0, stream>>>(bin, batch, g);
    gemm128_f32_kernel<<<(GRAPHS + 31) / 32, 256, 0, stream>>>(g, mw1, mb1, gh, GRAPHS);
    final_kernel<<<(GRAPHS * 16 + 255) / 256, 256, 0, stream>>>(gh, mw2, mb2, out);
}

// Round 11
// 265.920 us; speedup vs baseline: 1.8505x; 1.0576x over previous
//
#include <hip/hip_runtime.h>

#define NODES   50000
#define EDGES   800000
#define GRAPHS  500
#define HID     128
#define OUTC    10
#define NLAYERS 3
#define ELLCAP  64

typedef __bf16 bf16x8 __attribute__((ext_vector_type(8)));
typedef float  f32x4  __attribute__((ext_vector_type(4)));

__device__ __forceinline__ unsigned short f2bf(float f){
    unsigned u = __float_as_uint(f);
    u = (u + 0x7fffu + ((u >> 16) & 1u)) >> 16;
    return (unsigned short)u;
}
__device__ __forceinline__ float bf2f(unsigned short h){
    return __uint_as_float(((unsigned)h) << 16);
}

#define FILLB  ((EDGES + 255) / 256)            // 3125
#define PREPB  ((6 * HID * HID + 255) / 256)    // 384
#define CONVB  ((NODES * 64 + 255) / 256)       // 12500

// ---------------------------------------------------------------------------
// Fused setup: transposed-ELL fill | weight transpose+bf16 | x->bf16.
// ell layout: ell[slot][node] (slot-major) -> scatter stays L2-resident.
// ---------------------------------------------------------------------------
__global__ __launch_bounds__(256) void setup_kernel(
    const int* __restrict__ src, const int* __restrict__ dst,
    int* __restrict__ deg, unsigned short* __restrict__ ell,
    const float* __restrict__ w1, const float* __restrict__ w2,
    unsigned short* __restrict__ wt,
    const float* __restrict__ x, unsigned* __restrict__ xb)
{
    const int b = blockIdx.x;
    if (b < FILLB) {
        int e = b * 256 + threadIdx.x;
        if (e < EDGES) {
            int d = dst[e];
            int pos = atomicAdd(&deg[d], 1);
            if (pos < ELLCAP)
                ell[(size_t)pos * NODES + d] = (unsigned short)src[e];
        }
    } else if (b < FILLB + PREPB) {
        int idx = (b - FILLB) * 256 + threadIdx.x;
        if (idx < 6 * HID * HID) {
            int m = idx >> 14;
            int n = (idx >> 7) & 127;
            int k = idx & 127;
            const float* w = (m < 3) ? (w1 + (size_t)m * HID * HID)
                                     : (w2 + (size_t)(m - 3) * HID * HID);
            wt[idx] = f2bf(w[(size_t)k * HID + n]);
        }
    } else {
        int i = (b - FILLB - PREPB) * 256 + threadIdx.x;   // f32 pair index
        if (i < NODES * 64) {
            float2 v = reinterpret_cast<const float2*>(x)[i];
            xb[i] = ((unsigned)f2bf(v.y) << 16) | f2bf(v.x);
        }
    }
}

// ---------------------------------------------------------------------------
// Fused GIN layer, 32-row tile, 512 threads (8 waves):
//   gather: wave w gathers rows w*4..w*4+3 -> LDS
//   GEMM:   wave w computes row-group (w>>2)*16 x col-quarter (w&3)*32
// Rows are SHARED between 4 waves (same rg, different cq), so a barrier is
// required between GEMM1's A-fragment loads and the h1 LDS write-back
// (the round-10 race: one wave's h1 write clobbered another's A reads).
// ---------------------------------------------------------------------------
__global__ __launch_bounds__(512) void layer_kernel(
    const unsigned short* __restrict__ X,
    const int* __restrict__ deg, const unsigned short* __restrict__ ell,
    const unsigned short* __restrict__ Wt1, const float* __restrict__ bias1,
    const unsigned short* __restrict__ Wt2, const float* __restrict__ bias2,
    unsigned short* __restrict__ C)
{
    __shared__ unsigned short As[32][136];
    const int tid  = threadIdx.x;
    const int w    = tid >> 6;          // wave 0..7
    const int lane = tid & 63;
    const int q    = lane >> 4;         // quarter -> neighbor slot / k-chunk
    const int lr   = lane & 15;         // 16B chunk within row / mfma row
    const int row0 = blockIdx.x * 32;

    const uint4* xr = reinterpret_cast<const uint4*>(X);   // 16 uint4 per row

    // ---- gather: this wave's 4 rows ----
    for (int i = 0; i < 4; ++i) {
        const int row = w * 4 + i;
        int n = row0 + row;
        if (n >= NODES) n = NODES - 1;      // tail: redundant compute, store guarded

        float acc[8];
        #pragma unroll
        for (int k = 0; k < 8; ++k) acc[k] = 0.f;

        const int dg = min(deg[n], ELLCAP);
        for (int e0 = 0; e0 < dg; e0 += 16) {
            uint4 v[4];
            unsigned m[4];
            #pragma unroll
            for (int j = 0; j < 4; ++j) {
                int e = e0 + 4 * j + q;
                bool ok = e < dg;
                m[j] = ok ? 0xffffffffu : 0u;
                int ec = ok ? e : (dg - 1);
                int s = ell[(size_t)ec * NODES + n];
                v[j] = xr[(size_t)s * 16 + lr];
            }
            #pragma unroll
            for (int j = 0; j < 4; ++j) {
                const unsigned uu[4] = {v[j].x, v[j].y, v[j].z, v[j].w};
                #pragma unroll
                for (int k2 = 0; k2 < 4; ++k2) {
                    unsigned uv = uu[k2] & m[j];
                    acc[2 * k2]     += __uint_as_float(uv << 16);
                    acc[2 * k2 + 1] += __uint_as_float(uv & 0xffff0000u);
                }
            }
        }

        #pragma unroll
        for (int k = 0; k < 8; ++k) {
            acc[k] += __shfl_xor(acc[k], 16, 64);
            acc[k] += __shfl_xor(acc[k], 32, 64);
        }

        if (q == 0) {
            uint4 self = xr[(size_t)n * 16 + lr];
            const unsigned su[4] = {self.x, self.y, self.z, self.w};
            uint4 o;
            unsigned* ou = &o.x;
            #pragma unroll
            for (int j = 0; j < 4; ++j) {
                float c0 = acc[2 * j]     + __uint_as_float(su[j] << 16);
                float c1 = acc[2 * j + 1] + __uint_as_float(su[j] & 0xffff0000u);
                ou[j] = ((unsigned)f2bf(c1) << 16) | f2bf(c0);
            }
            *reinterpret_cast<uint4*>(&As[row][lr * 8]) = o;
        }
    }
    __syncthreads();

    const int rg = w >> 2;              // row-group 0..1
    const int cq = w & 3;               // col-quarter 0..3
    const int ar = rg * 16 + lr;        // this wave's mfma row in tile

    bf16x8 af[4];
    f32x4 acc[2];

    // ---- GEMM 1: h1[16 x 32-quarter] ----
    #pragma unroll
    for (int s = 0; s < 4; ++s)
        af[s] = *reinterpret_cast<const bf16x8*>(&As[ar][s * 32 + q * 8]);
    __syncthreads();   // all waves done READING As before any h1 write-back

    #pragma unroll
    for (int nt = 0; nt < 2; ++nt) acc[nt] = (f32x4){0.f, 0.f, 0.f, 0.f};
    {
        #pragma unroll
        for (int nt = 0; nt < 2; ++nt) {
            const unsigned short* wn = Wt1 + (size_t)(cq * 32 + nt * 16 + lr) * HID + q * 8;
            #pragma unroll
            for (int s = 0; s < 4; ++s) {
                bf16x8 b = *reinterpret_cast<const bf16x8*>(wn + s * 32);
                acc[nt] = __builtin_amdgcn_mfma_f32_16x16x32_bf16(b, af[s], acc[nt], 0, 0, 0);
            }
        }
    }

    // bias1 + relu -> h1 into LDS (own rows x own col-quarter)
    {
        const float4* b4p = reinterpret_cast<const float4*>(bias1);
        #pragma unroll
        for (int nt = 0; nt < 2; ++nt) {
            int col = cq * 32 + nt * 16 + q * 4;
            float4 b4 = b4p[col >> 2];
            ushort4 o;
            o.x = f2bf(fmaxf(acc[nt][0] + b4.x, 0.f));
            o.y = f2bf(fmaxf(acc[nt][1] + b4.y, 0.f));
            o.z = f2bf(fmaxf(acc[nt][2] + b4.z, 0.f));
            o.w = f2bf(fmaxf(acc[nt][3] + b4.w, 0.f));
            *reinterpret_cast<ushort4*>(&As[ar][col]) = o;
        }
    }
    __syncthreads();

    // ---- GEMM 2 ----
    #pragma unroll
    for (int s = 0; s < 4; ++s)
        af[s] = *reinterpret_cast<const bf16x8*>(&As[ar][s * 32 + q * 8]);
    #pragma unroll
    for (int nt = 0; nt < 2; ++nt) acc[nt] = (f32x4){0.f, 0.f, 0.f, 0.f};
    {
        #pragma unroll
        for (int nt = 0; nt < 2; ++nt) {
            const unsigned short* wn = Wt2 + (size_t)(cq * 32 + nt * 16 + lr) * HID + q * 8;
            #pragma unroll
            for (int s = 0; s < 4; ++s) {
                bf16x8 b = *reinterpret_cast<const bf16x8*>(wn + s * 32);
                acc[nt] = __builtin_amdgcn_mfma_f32_16x16x32_bf16(b, af[s], acc[nt], 0, 0, 0);
            }
        }
    }

    const int row = row0 + ar;
    if (row < NODES) {
        const float4* b4p = reinterpret_cast<const float4*>(bias2);
        #pragma unroll
        for (int nt = 0; nt < 2; ++nt) {
            int col = cq * 32 + nt * 16 + q * 4;
            float4 b4 = b4p[col >> 2];
            ushort4 o;
            o.x = f2bf(fmaxf(acc[nt][0] + b4.x, 0.f));
            o.y = f2bf(fmaxf(acc[nt][1] + b4.y, 0.f));
            o.z = f2bf(fmaxf(acc[nt][2] + b4.z, 0.f));
            o.w = f2bf(fmaxf(acc[nt][3] + b4.w, 0.f));
            *reinterpret_cast<ushort4*>(C + (size_t)row * HID + col) = o;
        }
    }
}

// ---------------------------------------------------------------------------
// Pool over sorted batch ids (bf16 in, f32 out)
// ---------------------------------------------------------------------------
__device__ __forceinline__ int lbound(const int* __restrict__ a, int v)
{
    int lo = 0, hi = NODES;
    while (lo < hi) {
        int m = (lo + hi) >> 1;
        if (a[m] < v) lo = m + 1; else hi = m;
    }
    return lo;
}

__global__ __launch_bounds__(256) void pool_sorted_kernel(
    const unsigned short* __restrict__ x,
    const int* __restrict__ batch,
    float* __restrict__ g)
{
    const int gid = blockIdx.x;
    const int beg = lbound(batch, gid);
    const int end = lbound(batch, gid + 1);

    const int c    = threadIdx.x & 127;
    const int half = threadIdx.x >> 7;

    float acc = 0.f;
    for (int r = beg + half; r < end; r += 2)
        acc += bf2f(x[(size_t)r * HID + c]);

    __shared__ float lds[256];
    lds[threadIdx.x] = acc;
    __syncthreads();
    if (threadIdx.x < 128)
        g[(size_t)gid * HID + threadIdx.x] = lds[threadIdx.x] + lds[threadIdx.x + 128];
}

// ---------------------------------------------------------------------------
// Small f32 GEMM for the graph-level MLP (M=500)
// ---------------------------------------------------------------------------
__global__ __launch_bounds__(256) void gemm128_f32_kernel(
    const float* __restrict__ A,
    const float* __restrict__ W,
    const float* __restrict__ bias,
    float* __restrict__ C,
    int M)
{
    __shared__ float As[32][HID];
    const int tid  = threadIdx.x;
    const int row0 = blockIdx.x * 32;

    {
        const int r = tid >> 3;
        const int c = (tid & 7) * 16;
        const int gr = row0 + r;
        float4* ps = reinterpret_cast<float4*>(&As[r][c]);
        if (gr < M) {
            const float4* pa = reinterpret_cast<const float4*>(A + (size_t)gr * HID + c);
            #pragma unroll
            for (int j = 0; j < 4; ++j) ps[j] = pa[j];
        } else {
            #pragma unroll
            for (int j = 0; j < 4; ++j) ps[j] = make_float4(0.f, 0.f, 0.f, 0.f);
        }
    }
    __syncthreads();

    const int tx = tid & 31;
    const int ty = tid >> 5;

    float4 acc[4];
    #pragma unroll
    for (int i = 0; i < 4; ++i) acc[i] = make_float4(0.f, 0.f, 0.f, 0.f);

    #pragma unroll 4
    for (int k = 0; k < HID; ++k) {
        const float4 w = *reinterpret_cast<const float4*>(W + (size_t)k * HID + tx * 4);
        #pragma unroll
        for (int i = 0; i < 4; ++i) {
            const float a = As[ty + 8 * i][k];
            acc[i].x += a * w.x;
            acc[i].y += a * w.y;
            acc[i].z += a * w.z;
            acc[i].w += a * w.w;
        }
    }

    const float4 b4 = *reinterpret_cast<const float4*>(bias + tx * 4);
    #pragma unroll
    for (int i = 0; i < 4; ++i) {
        const int row = row0 + ty + 8 * i;
        if (row < M) {
            float4 o = make_float4(fmaxf(acc[i].x + b4.x, 0.f),
                                   fmaxf(acc[i].y + b4.y, 0.f),
                                   fmaxf(acc[i].z + b4.z, 0.f),
                                   fmaxf(acc[i].w + b4.w, 0.f));
            *reinterpret_cast<float4*>(C + (size_t)row * HID + tx * 4) = o;
        }
    }
}

__global__ __launch_bounds__(256) void final_kernel(
    const float* __restrict__ gh,
    const float* __restrict__ w2,
    const float* __restrict__ b2,
    float* __restrict__ out)
{
    int idx = blockIdx.x * 256 + threadIdx.x;
    int r = idx >> 4;
    int c = idx & 15;
    if (r >= GRAPHS || c >= OUTC) return;
    float acc = b2[c];
    for (int k = 0; k < HID; ++k)
        acc += gh[(size_t)r * HID + k] * w2[(size_t)k * OUTC + c];
    out[(size_t)r * OUTC + c] = acc;
}

// ---------------------------------------------------------------------------
extern "C" void kernel_launch(void* const* d_in, const int* in_sizes, int n_in,
                              void* d_out, int out_size, void* d_ws, size_t ws_size,
                              hipStream_t stream)
{
    const float* x    = (const float*)d_in[0];
    const float* w1   = (const float*)d_in[1];
    const float* b1   = (const float*)d_in[2];
    const float* w2   = (const float*)d_in[3];
    const float* b2   = (const float*)d_in[4];
    const float* mw1  = (const float*)d_in[5];
    const float* mb1  = (const float*)d_in[6];
    const float* mw2  = (const float*)d_in[7];
    const float* mb2  = (const float*)d_in[8];
    const int*   ei   = (const int*)d_in[9];
    const int*   batch= (const int*)d_in[10];
    float* out = (float*)d_out;

    // workspace layout
    char* p = (char*)d_ws;
    unsigned short* buf0 = (unsigned short*)p;  p += (size_t)NODES * HID * 2;
    unsigned short* buf1 = (unsigned short*)p;  p += (size_t)NODES * HID * 2;
    unsigned short* ell  = (unsigned short*)p;  p += (size_t)NODES * ELLCAP * 2;
    unsigned short* wt   = (unsigned short*)p;  p += (size_t)6 * HID * HID * 2;
    float* g      = (float*)p;                  p += (size_t)GRAPHS * HID * 4;
    float* gh     = (float*)p;                  p += (size_t)GRAPHS * HID * 4;
    int*   deg    = (int*)p;                    p += (size_t)NODES * 4;

    const int* src = ei;
    const int* dst = ei + EDGES;

    const int layerBlocks = (NODES + 31) / 32;          // 1563
    const int setupBlocks = FILLB + PREPB + CONVB;      // 16009

    // ---- setup: ELL fill + weight prep + x->bf16, co-scheduled ----
    hipMemsetAsync(deg, 0, (size_t)NODES * sizeof(int), stream);
    setup_kernel<<<setupBlocks, 256, 0, stream>>>(
        src, dst, deg, ell, w1, w2, wt, x, (unsigned*)buf0);

    // ---- 3 fused GIN layers (gather + dual GEMM), ping-pong buf0/buf1 ----
    unsigned short* bin  = buf0;
    unsigned short* bout = buf1;
    for (int l = 0; l < NLAYERS; ++l) {
        layer_kernel<<<layerBlocks, 512, 0, stream>>>(
            bin, deg, ell,
            wt + (size_t)l * HID * HID,       b1 + (size_t)l * HID,
            wt + (size_t)(l + 3) * HID * HID, b2 + (size_t)l * HID,
            bout);
        unsigned short* t = bin; bin = bout; bout = t;
    }

    // ---- pool + MLP ----
    pool_sorted_kernel<<<GRAPHS, 256, 0, stream>>>(bin, batch, g);
    gemm128_f32_kernel<<<(GRAPHS + 31) / 32, 256, 0, stream>>>(g, mw1, mb1, gh, GRAPHS);
    final_kernel<<<(GRAPHS * 16 + 255) / 256, 256, 0, stream>>>(gh, mw2, mb2, out);
}

// Round 12
// 256.777 us; speedup vs baseline: 1.9164x; 1.0356x over previous
//
#include <hip/hip_runtime.h>

#define NODES   50000
#define EDGES   800000
#define GRAPHS  500
#define HID     128
#define OUTC    10
#define NLAYERS 3
#define ELLCAP  64

typedef __bf16 bf16x8 __attribute__((ext_vector_type(8)));
typedef float  f32x4  __attribute__((ext_vector_type(4)));

__device__ __forceinline__ unsigned short f2bf(float f){
    unsigned u = __float_as_uint(f);
    u = (u + 0x7fffu + ((u >> 16) & 1u)) >> 16;
    return (unsigned short)u;
}
__device__ __forceinline__ float bf2f(unsigned short h){
    return __uint_as_float(((unsigned)h) << 16);
}

#define FILLB  ((EDGES + 255) / 256)            // 3125
#define PREPB  ((6 * HID * HID + 255) / 256)    // 384
#define CONVB  ((NODES * 64 + 255) / 256)       // 12500

// ---------------------------------------------------------------------------
// Fused setup: transposed-ELL fill | weight transpose+bf16 | x->bf16.
// ell layout: ell[slot][node] (slot-major) -> scatter stays L2-resident AND
// a 32-node tile's indices for one slot are a single 64B line (coalesced
// staging in layer_kernel).
// ---------------------------------------------------------------------------
__global__ __launch_bounds__(256) void setup_kernel(
    const int* __restrict__ src, const int* __restrict__ dst,
    int* __restrict__ deg, unsigned short* __restrict__ ell,
    const float* __restrict__ w1, const float* __restrict__ w2,
    unsigned short* __restrict__ wt,
    const float* __restrict__ x, unsigned* __restrict__ xb)
{
    const int b = blockIdx.x;
    if (b < FILLB) {
        int e = b * 256 + threadIdx.x;
        if (e < EDGES) {
            int d = dst[e];
            int pos = atomicAdd(&deg[d], 1);
            if (pos < ELLCAP)
                ell[(size_t)pos * NODES + d] = (unsigned short)src[e];
        }
    } else if (b < FILLB + PREPB) {
        int idx = (b - FILLB) * 256 + threadIdx.x;
        if (idx < 6 * HID * HID) {
            int m = idx >> 14;
            int n = (idx >> 7) & 127;
            int k = idx & 127;
            const float* w = (m < 3) ? (w1 + (size_t)m * HID * HID)
                                     : (w2 + (size_t)(m - 3) * HID * HID);
            wt[idx] = f2bf(w[(size_t)k * HID + n]);
        }
    } else {
        int i = (b - FILLB - PREPB) * 256 + threadIdx.x;   // f32 pair index
        if (i < NODES * 64) {
            float2 v = reinterpret_cast<const float2*>(x)[i];
            xb[i] = ((unsigned)f2bf(v.y) << 16) | f2bf(v.x);
        }
    }
}

// ---------------------------------------------------------------------------
// Fused GIN layer, 32-row tile, 512 threads (8 waves):
//   phase 0: cooperative stage of deg[32] + ELL indices (<=64 slots x 32
//            nodes, coalesced 64B/slot) into LDS; block max-deg bounds loop.
//   gather:  wave w gathers rows w*4..w*4+3 -> LDS; indices come from LDS so
//            the random x-row load is a single-hop latency chain.
//   GEMM:    wave w computes row-group (w>>2)*16 x col-quarter (w&3)*32
//            of  C = relu( relu(hin@W1+b1) @ W2 + b2 )
// Barrier between GEMM1 A-frag loads and h1 write-back (rows shared by 4
// waves -- round-10 race).
// ---------------------------------------------------------------------------
__global__ __launch_bounds__(512) void layer_kernel(
    const unsigned short* __restrict__ X,
    const int* __restrict__ deg, const unsigned short* __restrict__ ell,
    const unsigned short* __restrict__ Wt1, const float* __restrict__ bias1,
    const unsigned short* __restrict__ Wt2, const float* __restrict__ bias2,
    unsigned short* __restrict__ C)
{
    __shared__ unsigned short As[32][136];
    __shared__ unsigned short idx_s[ELLCAP][32];   // [slot][node-in-tile], 4 KB
    __shared__ int deg_s[32];
    const int tid  = threadIdx.x;
    const int w    = tid >> 6;          // wave 0..7
    const int lane = tid & 63;
    const int q    = lane >> 4;         // quarter -> neighbor slot / k-chunk
    const int lr   = lane & 15;         // 16B chunk within row / mfma row
    const int row0 = blockIdx.x * 32;

    const uint4* xr = reinterpret_cast<const uint4*>(X);   // 16 uint4 per row

    // ---- phase 0a: stage degrees ----
    if (tid < 32) {
        int n = row0 + tid;
        if (n >= NODES) n = NODES - 1;
        deg_s[tid] = min(deg[n], ELLCAP);
    }
    __syncthreads();

    // block max degree (uniform LDS scan -- broadcast reads, cheap)
    int maxd = 0;
    #pragma unroll
    for (int i = 0; i < 32; ++i) maxd = max(maxd, deg_s[i]);

    // ---- phase 0b: stage indices, 16 slots per iteration, coalesced ----
    {
        const int sl0 = tid >> 5;          // 0..15
        const int nn  = tid & 31;
        int gn = row0 + nn;
        if (gn >= NODES) gn = NODES - 1;
        for (int s = sl0; s < maxd; s += 16)
            idx_s[s][nn] = ell[(size_t)s * NODES + gn];
    }
    __syncthreads();

    // ---- gather: this wave's 4 rows (single-hop random loads) ----
    for (int i = 0; i < 4; ++i) {
        const int row = w * 4 + i;
        int n = row0 + row;
        if (n >= NODES) n = NODES - 1;      // tail: redundant compute, store guarded

        float acc[8];
        #pragma unroll
        for (int k = 0; k < 8; ++k) acc[k] = 0.f;

        const int dg = deg_s[row];
        for (int e0 = 0; e0 < dg; e0 += 16) {
            uint4 v[4];
            unsigned m[4];
            #pragma unroll
            for (int j = 0; j < 4; ++j) {
                int e = e0 + 4 * j + q;
                bool ok = e < dg;
                m[j] = ok ? 0xffffffffu : 0u;
                int ec = ok ? e : (dg - 1);
                int s = idx_s[ec][row];
                v[j] = xr[(size_t)s * 16 + lr];
            }
            #pragma unroll
            for (int j = 0; j < 4; ++j) {
                const unsigned uu[4] = {v[j].x, v[j].y, v[j].z, v[j].w};
                #pragma unroll
                for (int k2 = 0; k2 < 4; ++k2) {
                    unsigned uv = uu[k2] & m[j];
                    acc[2 * k2]     += __uint_as_float(uv << 16);
                    acc[2 * k2 + 1] += __uint_as_float(uv & 0xffff0000u);
                }
            }
        }

        #pragma unroll
        for (int k = 0; k < 8; ++k) {
            acc[k] += __shfl_xor(acc[k], 16, 64);
            acc[k] += __shfl_xor(acc[k], 32, 64);
        }

        if (q == 0) {
            uint4 self = xr[(size_t)n * 16 + lr];
            const unsigned su[4] = {self.x, self.y, self.z, self.w};
            uint4 o;
            unsigned* ou = &o.x;
            #pragma unroll
            for (int j = 0; j < 4; ++j) {
                float c0 = acc[2 * j]     + __uint_as_float(su[j] << 16);
                float c1 = acc[2 * j + 1] + __uint_as_float(su[j] & 0xffff0000u);
                ou[j] = ((unsigned)f2bf(c1) << 16) | f2bf(c0);
            }
            *reinterpret_cast<uint4*>(&As[row][lr * 8]) = o;
        }
    }
    __syncthreads();

    const int rg = w >> 2;              // row-group 0..1
    const int cq = w & 3;               // col-quarter 0..3
    const int ar = rg * 16 + lr;        // this wave's mfma row in tile

    bf16x8 af[4];
    f32x4 acc[2];

    // ---- GEMM 1: h1[16 x 32-quarter] ----
    #pragma unroll
    for (int s = 0; s < 4; ++s)
        af[s] = *reinterpret_cast<const bf16x8*>(&As[ar][s * 32 + q * 8]);
    __syncthreads();   // all waves done READING As before any h1 write-back

    #pragma unroll
    for (int nt = 0; nt < 2; ++nt) acc[nt] = (f32x4){0.f, 0.f, 0.f, 0.f};
    {
        #pragma unroll
        for (int nt = 0; nt < 2; ++nt) {
            const unsigned short* wn = Wt1 + (size_t)(cq * 32 + nt * 16 + lr) * HID + q * 8;
            #pragma unroll
            for (int s = 0; s < 4; ++s) {
                bf16x8 b = *reinterpret_cast<const bf16x8*>(wn + s * 32);
                acc[nt] = __builtin_amdgcn_mfma_f32_16x16x32_bf16(b, af[s], acc[nt], 0, 0, 0);
            }
        }
    }

    // bias1 + relu -> h1 into LDS (own rows x own col-quarter)
    {
        const float4* b4p = reinterpret_cast<const float4*>(bias1);
        #pragma unroll
        for (int nt = 0; nt < 2; ++nt) {
            int col = cq * 32 + nt * 16 + q * 4;
            float4 b4 = b4p[col >> 2];
            ushort4 o;
            o.x = f2bf(fmaxf(acc[nt][0] + b4.x, 0.f));
            o.y = f2bf(fmaxf(acc[nt][1] + b4.y, 0.f));
            o.z = f2bf(fmaxf(acc[nt][2] + b4.z, 0.f));
            o.w = f2bf(fmaxf(acc[nt][3] + b4.w, 0.f));
            *reinterpret_cast<ushort4*>(&As[ar][col]) = o;
        }
    }
    __syncthreads();

    // ---- GEMM 2 ----
    #pragma unroll
    for (int s = 0; s < 4; ++s)
        af[s] = *reinterpret_cast<const bf16x8*>(&As[ar][s * 32 + q * 8]);
    #pragma unroll
    for (int nt = 0; nt < 2; ++nt) acc[nt] = (f32x4){0.f, 0.f, 0.f, 0.f};
    {
        #pragma unroll
        for (int nt = 0; nt < 2; ++nt) {
            const unsigned short* wn = Wt2 + (size_t)(cq * 32 + nt * 16 + lr) * HID + q * 8;
            #pragma unroll
            for (int s = 0; s < 4; ++s) {
                bf16x8 b = *reinterpret_cast<const bf16x8*>(wn + s * 32);
                acc[nt] = __builtin_amdgcn_mfma_f32_16x16x32_bf16(b, af[s], acc[nt], 0, 0, 0);
            }
        }
    }

    const int row = row0 + ar;
    if (row < NODES) {
        const float4* b4p = reinterpret_cast<const float4*>(bias2);
        #pragma unroll
        for (int nt = 0; nt < 2; ++nt) {
            int col = cq * 32 + nt * 16 + q * 4;
            float4 b4 = b4p[col >> 2];
            ushort4 o;
            o.x = f2bf(fmaxf(acc[nt][0] + b4.x, 0.f));
            o.y = f2bf(fmaxf(acc[nt][1] + b4.y, 0.f));
            o.z = f2bf(fmaxf(acc[nt][2] + b4.z, 0.f));
            o.w = f2bf(fmaxf(acc[nt][3] + b4.w, 0.f));
            *reinterpret_cast<ushort4*>(C + (size_t)row * HID + col) = o;
        }
    }
}

// ---------------------------------------------------------------------------
// Pool over sorted batch ids (bf16 in, f32 out)
// ---------------------------------------------------------------------------
__device__ __forceinline__ int lbound(const int* __restrict__ a, int v)
{
    int lo = 0, hi = NODES;
    while (lo < hi) {
        int m = (lo + hi) >> 1;
        if (a[m] < v) lo = m + 1; else hi = m;
    }
    return lo;
}

__global__ __launch_bounds__(256) void pool_sorted_kernel(
    const unsigned short* __restrict__ x,
    const int* __restrict__ batch,
    float* __restrict__ g)
{
    const int gid = blockIdx.x;
    const int beg = lbound(batch, gid);
    const int end = lbound(batch, gid + 1);

    const int c    = threadIdx.x & 127;
    const int half = threadIdx.x >> 7;

    float acc = 0.f;
    for (int r = beg + half; r < end; r += 2)
        acc += bf2f(x[(size_t)r * HID + c]);

    __shared__ float lds[256];
    lds[threadIdx.x] = acc;
    __syncthreads();
    if (threadIdx.x < 128)
        g[(size_t)gid * HID + threadIdx.x] = lds[threadIdx.x] + lds[threadIdx.x + 128];
}

// ---------------------------------------------------------------------------
// Small f32 GEMM for the graph-level MLP (M=500)
// ---------------------------------------------------------------------------
__global__ __launch_bounds__(256) void gemm128_f32_kernel(
    const float* __restrict__ A,
    const float* __restrict__ W,
    const float* __restrict__ bias,
    float* __restrict__ C,
    int M)
{
    __shared__ float As[32][HID];
    const int tid  = threadIdx.x;
    const int row0 = blockIdx.x * 32;

    {
        const int r = tid >> 3;
        const int c = (tid & 7) * 16;
        const int gr = row0 + r;
        float4* ps = reinterpret_cast<float4*>(&As[r][c]);
        if (gr < M) {
            const float4* pa = reinterpret_cast<const float4*>(A + (size_t)gr * HID + c);
            #pragma unroll
            for (int j = 0; j < 4; ++j) ps[j] = pa[j];
        } else {
            #pragma unroll
            for (int j = 0; j < 4; ++j) ps[j] = make_float4(0.f, 0.f, 0.f, 0.f);
        }
    }
    __syncthreads();

    const int tx = tid & 31;
    const int ty = tid >> 5;

    float4 acc[4];
    #pragma unroll
    for (int i = 0; i < 4; ++i) acc[i] = make_float4(0.f, 0.f, 0.f, 0.f);

    #pragma unroll 4
    for (int k = 0; k < HID; ++k) {
        const float4 w = *reinterpret_cast<const float4*>(W + (size_t)k * HID + tx * 4);
        #pragma unroll
        for (int i = 0; i < 4; ++i) {
            const float a = As[ty + 8 * i][k];
            acc[i].x += a * w.x;
            acc[i].y += a * w.y;
            acc[i].z += a * w.z;
            acc[i].w += a * w.w;
        }
    }

    const float4 b4 = *reinterpret_cast<const float4*>(bias + tx * 4);
    #pragma unroll
    for (int i = 0; i < 4; ++i) {
        const int row = row0 + ty + 8 * i;
        if (row < M) {
            float4 o = make_float4(fmaxf(acc[i].x + b4.x, 0.f),
                                   fmaxf(acc[i].y + b4.y, 0.f),
                                   fmaxf(acc[i].z + b4.z, 0.f),
                                   fmaxf(acc[i].w + b4.w, 0.f));
            *reinterpret_cast<float4*>(C + (size_t)row * HID + tx * 4) = o;
        }
    }
}

__global__ __launch_bounds__(256) void final_kernel(
    const float* __restrict__ gh,
    const float* __restrict__ w2,
    const float* __restrict__ b2,
    float* __restrict__ out)
{
    int idx = blockIdx.x * 256 + threadIdx.x;
    int r = idx >> 4;
    int c = idx & 15;
    if (r >= GRAPHS || c >= OUTC) return;
    float acc = b2[c];
    for (int k = 0; k < HID; ++k)
        acc += gh[(size_t)r * HID + k] * w2[(size_t)k * OUTC + c];
    out[(size_t)r * OUTC + c] = acc;
}

// ---------------------------------------------------------------------------
extern "C" void kernel_launch(void* const* d_in, const int* in_sizes, int n_in,
                              void* d_out, int out_size, void* d_ws, size_t ws_size,
                              hipStream_t stream)
{
    const float* x    = (const float*)d_in[0];
    const float* w1   = (const float*)d_in[1];
    const float* b1   = (const float*)d_in[2];
    const float* w2   = (const float*)d_in[3];
    const float* b2   = (const float*)d_in[4];
    const float* mw1  = (const float*)d_in[5];
    const float* mb1  = (const float*)d_in[6];
    const float* mw2  = (const float*)d_in[7];
    const float* mb2  = (const float*)d_in[8];
    const int*   ei   = (const int*)d_in[9];
    const int*   batch= (const int*)d_in[10];
    float* out = (float*)d_out;

    // workspace layout
    char* p = (char*)d_ws;
    unsigned short* buf0 = (unsigned short*)p;  p += (size_t)NODES * HID * 2;
    unsigned short* buf1 = (unsigned short*)p;  p += (size_t)NODES * HID * 2;
    unsigned short* ell  = (unsigned short*)p;  p += (size_t)NODES * ELLCAP * 2;
    unsigned short* wt   = (unsigned short*)p;  p += (size_t)6 * HID * HID * 2;
    float* g      = (float*)p;                  p += (size_t)GRAPHS * HID * 4;
    float* gh     = (float*)p;                  p += (size_t)GRAPHS * HID * 4;
    int*   deg    = (int*)p;                    p += (size_t)NODES * 4;

    const int* src = ei;
    const int* dst = ei + EDGES;

    const int layerBlocks = (NODES + 31) / 32;          // 1563
    const int setupBlocks = FILLB + PREPB + CONVB;      // 16009

    // ---- setup: ELL fill + weight prep + x->bf16, co-scheduled ----
    hipMemsetAsync(deg, 0, (size_t)NODES * sizeof(int), stream);
    setup_kernel<<<setupBlocks, 256, 0, stream>>>(
        src, dst, deg, ell, w1, w2, wt, x, (unsigned*)buf0);

    // ---- 3 fused GIN layers (gather + dual GEMM), ping-pong buf0/buf1 ----
    unsigned short* bin  = buf0;
    unsigned short* bout = buf1;
    for (int l = 0; l < NLAYERS; ++l) {
        layer_kernel<<<layerBlocks, 512, 0, stream>>>(
            bin, deg, ell,
            wt + (size_t)l * HID * HID,       b1 + (size_t)l * HID,
            wt + (size_t)(l + 3) * HID * HID, b2 + (size_t)l * HID,
            bout);
        unsigned short* t = bin; bin = bout; bout = t;
    }

    // ---- pool + MLP ----
    pool_sorted_kernel<<<GRAPHS, 256, 0, stream>>>(bin, batch, g);
    gemm128_f32_kernel<<<(GRAPHS + 31) / 32, 256, 0, stream>>>(g, mw1, mb1, gh, GRAPHS);
    final_kernel<<<(GRAPHS * 16 + 255) / 256, 256, 0, stream>>>(gh, mw2, mb2, out);
}